// Round 1
// baseline (1642.971 us; speedup 1.0000x reference)
//
#include <hip/hip_runtime.h>
#include <math.h>

// Problem constants
#define V    20000
#define SCV  4000
#define DD   128
#define LL   15
#define OUTN (16384 * 128)   // B*S*D

#define LEAF_BIT 0x40000000
#define REF_MASK 0x3FFFFFFF

// ---- workspace layout (bytes) ----
// counts:   int[8]            @ 0
// rootSlot: int[V]            @ 256
// lists:    int4[240000]      @ 80384
// leafH:    float[SCV*128]    @ 3920384
// leafC:    float[SCV*128]    @ 5968384
// hInt:     float[V*7*128]    @ 8016384
// cInt:     float[V*7*128]    @ 79696384
// total ~151.4 MB
#define OFF_COUNTS 0
#define OFF_ROOT   256
#define OFF_LISTS  80384
#define OFF_LEAFH  3920384
#define OFF_LEAFC  5968384
#define OFF_HINT   8016384
#define OFF_CINT   79696384

__device__ __constant__ int d_listOff[8] = {0, 0, 80000, 120000, 160000, 180000, 200000, 220000};

__device__ __forceinline__ float sigm(float x) { return 1.0f / (1.0f + expf(-x)); }

// ---------------- leaf kernel: per sub-char-id leaf (h,c) ----------------
__global__ void leaf_kernel(const float* __restrict__ emb,
                            float* __restrict__ leafH, float* __restrict__ leafC) {
    int row = blockIdx.x;       // 0..SCV-1
    int i   = threadIdx.x;      // 0..127
    const float* e = emb + row * 640;
    float ig = e[i];
    float og = e[384 + i];
    float ug = e[512 + i];
    float c = sigm(ig) * tanhf(ug);
    float h = sigm(og) * tanhf(c);
    leafH[row * 128 + i] = h;
    leafC[row * 128 + i] = c;
}

// ---------------- metadata: heights, slots, per-round work lists ----------------
__global__ void meta_kernel(const int* __restrict__ node_ids,
                            const int* __restrict__ left,
                            const int* __restrict__ right,
                            const int* __restrict__ last,
                            int* __restrict__ counts,
                            int* __restrict__ rootSlot,
                            int4* __restrict__ lists) {
    __shared__ int sH[64][LL];
    __shared__ int sR[64][LL];
    int tid = threadIdx.x;
    int v = blockIdx.x * 64 + tid;
    if (v >= V) return;
    int lastv = last[v];
    int nInt = 0;
    for (int j = 0; j <= lastv; ++j) {
        int l = left[v * LL + j];
        if (l < 0) {
            sH[tid][j] = 0;
            sR[tid][j] = LEAF_BIT | node_ids[v * LL + j];
        } else {
            int r = right[v * LL + j];
            int hl = sH[tid][l], hr = sH[tid][r];
            int hh = 1 + (hl > hr ? hl : hr);
            sH[tid][j] = hh;
            int dst = v * 7 + nInt;
            int4 e;
            e.x = dst;
            e.y = node_ids[v * LL + j];
            e.z = sR[tid][l];
            e.w = sR[tid][r];
            int pos = atomicAdd(&counts[hh], 1);
            lists[d_listOff[hh] + pos] = e;
            sR[tid][j] = dst;
            nInt++;
        }
    }
    rootSlot[v] = v * 7 + nInt - 1;
}

// ---------------- gathered GEMM + LSTM epilogue for one height round ----------------
// 16 nodes per block. A = [hl | hr] per node (256), B = [Wl;Wr] (256x640).
__launch_bounds__(320)
__global__ void node_gemm(const int4* __restrict__ list, const int* __restrict__ countPtr,
                          const float* __restrict__ emb,
                          const float* __restrict__ Wl, const float* __restrict__ Wlb,
                          const float* __restrict__ Wr, const float* __restrict__ Wrb,
                          const float* __restrict__ leafH, const float* __restrict__ leafC,
                          float* __restrict__ hInt, float* __restrict__ cInt) {
    __shared__ float S[16 * 640];     // phase1: A tile in first 16*256; phase2: full s rows
    __shared__ float CLR[16 * 256];   // children c values (cl | cr)
    __shared__ int4 meta[16];

    int cnt = *countPtr;
    int base = (int)blockIdx.x * 16;
    if (base >= cnt) return;
    int rows = cnt - base;
    if (rows > 16) rows = 16;
    int t = threadIdx.x;

    if (t < 16) {
        int4 e;
        if (t < rows) e = list[base + t];
        else { e.x = 0; e.y = 0; e.z = LEAF_BIT; e.w = LEAF_BIT; }
        meta[t] = e;
    }
    __syncthreads();

    // stage A (h of children) and CLR (c of children)
    for (int idx = t; idx < 16 * 256; idx += 320) {
        int m = idx >> 8, k = idx & 255;
        int ref = (k < 128) ? meta[m].z : meta[m].w;
        int row = ref & REF_MASK;
        const float* hs = (ref & LEAF_BIT) ? leafH : hInt;
        const float* cs = (ref & LEAF_BIT) ? leafC : cInt;
        int src = row * 128 + (k & 127);
        S[(m << 8) + k] = hs[src];
        CLR[idx] = cs[src];
    }

    // acc init: emb row + both biases
    float bs0 = Wlb[t] + Wrb[t];
    float bs1 = Wlb[t + 320] + Wrb[t + 320];
    float acc0[16], acc1[16];
#pragma unroll
    for (int m = 0; m < 16; ++m) {
        const float* e = emb + meta[m].y * 640;
        acc0[m] = e[t] + bs0;
        acc1[m] = e[t + 320] + bs1;
    }
    __syncthreads();

    // K loop: half 0 = left child x Wl, half 1 = right child x Wr
#pragma unroll 1
    for (int half = 0; half < 2; ++half) {
        const float* __restrict__ Bp = half ? Wr : Wl;
        const float* Ab = S + half * 128;
#pragma unroll 1
        for (int kb = 0; kb < 128; kb += 4) {
            float4 a[16];
#pragma unroll
            for (int m = 0; m < 16; ++m) a[m] = *(const float4*)(Ab + (m << 8) + kb);
#pragma unroll
            for (int u = 0; u < 4; ++u) {
                float b0 = Bp[(kb + u) * 640 + t];
                float b1 = Bp[(kb + u) * 640 + t + 320];
#pragma unroll
                for (int m = 0; m < 16; ++m) {
                    float av = (&a[m].x)[u];
                    acc0[m] = fmaf(av, b0, acc0[m]);
                    acc1[m] = fmaf(av, b1, acc1[m]);
                }
            }
        }
    }

    __syncthreads();   // everyone done reading A region before overwriting with s
#pragma unroll
    for (int m = 0; m < 16; ++m) {
        S[m * 640 + t]       = acc0[m];
        S[m * 640 + t + 320] = acc1[m];
    }
    __syncthreads();

    // LSTM gate epilogue: s -> (c,h), scatter to this node's slot
    for (int it = t; it < 16 * 128; it += 320) {
        int m = it >> 7;
        if (m < rows) {
            int i = it & 127;
            const float* Sm = S + m * 640;
            float c = sigm(Sm[i]) * tanhf(Sm[512 + i])
                    + sigm(Sm[128 + i]) * CLR[(m << 8) + i]
                    + sigm(Sm[256 + i]) * CLR[(m << 8) + 128 + i];
            float h = sigm(Sm[384 + i]) * tanhf(c);
            int dst = meta[m].x;
            cInt[dst * 128 + i] = c;
            hInt[dst * 128 + i] = h;
        }
    }
}

// ---------------- final gather: out[b,s,:] = h_root[input[b,s]] ----------------
__global__ void gather_kernel(const int* __restrict__ input,
                              const int* __restrict__ rootSlot,
                              const float* __restrict__ hInt,
                              float* __restrict__ out) {
    int idx = blockIdx.x * 256 + threadIdx.x;   // < OUTN
    int token = input[idx >> 7];
    int d = idx & 127;
    out[idx] = hInt[rootSlot[token] * 128 + d];
}

extern "C" void kernel_launch(void* const* d_in, const int* in_sizes, int n_in,
                              void* d_out, int out_size, void* d_ws, size_t ws_size,
                              hipStream_t stream) {
    const int*   input    = (const int*)d_in[0];
    const int*   node_ids = (const int*)d_in[1];
    const int*   left     = (const int*)d_in[2];
    const int*   right    = (const int*)d_in[3];
    const int*   last     = (const int*)d_in[4];
    const float* emb      = (const float*)d_in[5];
    const float* Wl       = (const float*)d_in[6];
    const float* Wlb      = (const float*)d_in[7];
    const float* Wr       = (const float*)d_in[8];
    const float* Wrb      = (const float*)d_in[9];
    float* out = (float*)d_out;

    char* ws = (char*)d_ws;
    int*   counts   = (int*)(ws + OFF_COUNTS);
    int*   rootSlot = (int*)(ws + OFF_ROOT);
    int4*  lists    = (int4*)(ws + OFF_LISTS);
    float* leafH    = (float*)(ws + OFF_LEAFH);
    float* leafC    = (float*)(ws + OFF_LEAFC);
    float* hInt     = (float*)(ws + OFF_HINT);
    float* cInt     = (float*)(ws + OFF_CINT);

    hipMemsetAsync(counts, 0, 8 * sizeof(int), stream);

    leaf_kernel<<<SCV, 128, 0, stream>>>(emb, leafH, leafC);
    meta_kernel<<<(V + 63) / 64, 64, 0, stream>>>(node_ids, left, right, last,
                                                  counts, rootSlot, lists);

    static const int listOffH[7] = {0, 80000, 120000, 160000, 180000, 200000, 220000};
    static const int capsH[7]    = {80000, 40000, 40000, 20000, 20000, 20000, 20000};
    for (int h = 1; h <= 7; ++h) {
        int blocks = capsH[h - 1] / 16;
        node_gemm<<<blocks, 320, 0, stream>>>(lists + listOffH[h - 1], counts + h,
                                              emb, Wl, Wlb, Wr, Wrb,
                                              leafH, leafC, hInt, cInt);
    }

    gather_kernel<<<OUTN / 256, 256, 0, stream>>>(input, rootSlot, hInt, out);
}

// Round 2
// 793.418 us; speedup vs baseline: 2.0708x; 2.0708x over previous
//
#include <hip/hip_runtime.h>
#include <math.h>

// Problem constants
#define V    20000
#define SCV  4000
#define DD   128
#define LL   15
#define OUTN (16384 * 128)   // B*S*D

#define LEAF_BIT 0x40000000
#define REF_MASK 0x3FFFFFFF

// ---- workspace layout (bytes) ----
#define OFF_COUNTS 0
#define OFF_ROOT   256
#define OFF_LISTS  80384
#define OFF_LEAFH  3920384
#define OFF_LEAFC  5968384
#define OFF_HINT   8016384
#define OFF_CINT   79696384

__device__ __constant__ int d_listOff[8] = {0, 0, 80000, 120000, 160000, 180000, 200000, 220000};

__device__ __forceinline__ float sigm(float x) { return 1.0f / (1.0f + expf(-x)); }

// ---------------- leaf kernel: per sub-char-id leaf (h,c) ----------------
__global__ void leaf_kernel(const float* __restrict__ emb,
                            float* __restrict__ leafH, float* __restrict__ leafC) {
    int row = blockIdx.x;       // 0..SCV-1
    int i   = threadIdx.x;      // 0..127
    const float* e = emb + row * 640;
    float ig = e[i];
    float og = e[384 + i];
    float ug = e[512 + i];
    float c = sigm(ig) * tanhf(ug);
    float h = sigm(og) * tanhf(c);
    leafH[row * 128 + i] = h;
    leafC[row * 128 + i] = c;
}

// ---------------- metadata: heights, slots, per-round work lists ----------------
// Block-aggregated atomics: LDS atomicAdd for local pos, ONE global atomicAdd
// per height per block. 128 threads/block, register-prefetched tree rows.
#define MT 128
__global__ void meta_kernel(const int* __restrict__ node_ids,
                            const int* __restrict__ left,
                            const int* __restrict__ right,
                            const int* __restrict__ last,
                            int* __restrict__ counts,
                            int* __restrict__ rootSlot,
                            int4* __restrict__ lists) {
    __shared__ int  sHei[MT][17];
    __shared__ int  sRef[MT][17];
    __shared__ int4 ebuf[MT][7];
    __shared__ int  emeta[MT][7];
    __shared__ int  locCnt[8];
    __shared__ int  basePos[8];

    int tid = threadIdx.x;
    if (tid < 8) locCnt[tid] = 0;
    __syncthreads();

    int v = blockIdx.x * MT + tid;
    int nInt = 0;
    if (v < V) {
        int l15[LL], r15[LL], id15[LL];
#pragma unroll
        for (int j = 0; j < LL; ++j) {
            l15[j]  = left[v * LL + j];
            r15[j]  = right[v * LL + j];
            id15[j] = node_ids[v * LL + j];
        }
        int lastv = last[v];
#pragma unroll
        for (int j = 0; j < LL; ++j) {
            if (j <= lastv) {
                int l = l15[j];
                if (l < 0) {
                    sHei[tid][j] = 0;
                    sRef[tid][j] = LEAF_BIT | id15[j];
                } else {
                    int r = r15[j];
                    int hl = sHei[tid][l], hr = sHei[tid][r];
                    int hh = 1 + (hl > hr ? hl : hr);
                    sHei[tid][j] = hh;
                    int dst = v * 7 + nInt;
                    int pos = atomicAdd(&locCnt[hh], 1);   // LDS atomic
                    ebuf[tid][nInt]  = make_int4(dst, id15[j], sRef[tid][l], sRef[tid][r]);
                    emeta[tid][nInt] = (hh << 16) | pos;
                    sRef[tid][j] = dst;
                    ++nInt;
                }
            }
        }
        rootSlot[v] = v * 7 + nInt - 1;
    }
    __syncthreads();
    if (tid < 8) {
        int c = locCnt[tid];
        basePos[tid] = c ? atomicAdd(&counts[tid], c) : 0;  // one global atomic per height
    }
    __syncthreads();
    for (int e = 0; e < nInt; ++e) {
        int md  = emeta[tid][e];
        int hh  = md >> 16;
        int pos = md & 0xFFFF;
        lists[d_listOff[hh] + basePos[hh] + pos] = ebuf[tid][e];
    }
}

// ---------------- gathered GEMM + LSTM epilogue for one height round ----------------
// 16 nodes per block, 320 threads; thread owns cols (2t, 2t+1).
// LDS: A 16KB + CH 10KB + meta -> ~27KB -> 3 blocks/CU (15 waves), vs 2 before.
__launch_bounds__(320)
__global__ void node_gemm(const int4* __restrict__ list, const int* __restrict__ countPtr,
                          const float* __restrict__ emb,
                          const float* __restrict__ Wl, const float* __restrict__ Wlb,
                          const float* __restrict__ Wr, const float* __restrict__ Wrb,
                          const float* __restrict__ leafH, const float* __restrict__ leafC,
                          float* __restrict__ hInt, float* __restrict__ cInt) {
    __shared__ float A[16 * 256];     // children h: [hl | hr] per node
    __shared__ float CH[4 * 640];     // epilogue transpose chunk (4 rows of s)
    __shared__ int4  meta[16];

    int cnt = *countPtr;
    int base = (int)blockIdx.x * 16;
    if (base >= cnt) return;
    int rows = cnt - base;
    if (rows > 16) rows = 16;
    int t = threadIdx.x;

    if (t < 16) {
        int4 e;
        if (t < rows) e = list[base + t];
        else { e.x = 0; e.y = 0; e.z = LEAF_BIT; e.w = LEAF_BIT; }
        meta[t] = e;
    }
    __syncthreads();

    // stage A (h of children)
    for (int idx = t; idx < 16 * 256; idx += 320) {
        int m = idx >> 8, k = idx & 255;
        int ref = (k < 128) ? meta[m].z : meta[m].w;
        const float* hs = (ref & LEAF_BIT) ? leafH : hInt;
        A[idx] = hs[(ref & REF_MASK) * 128 + (k & 127)];
    }

    // acc init: emb row + both biases; cols 2t, 2t+1
    float bs0 = Wlb[2 * t] + Wrb[2 * t];
    float bs1 = Wlb[2 * t + 1] + Wrb[2 * t + 1];
    float acc0[16], acc1[16];
#pragma unroll
    for (int m = 0; m < 16; ++m) {
        const float* e = emb + meta[m].y * 640;
        acc0[m] = e[2 * t] + bs0;
        acc1[m] = e[2 * t + 1] + bs1;
    }
    __syncthreads();

    // K loop: half 0 = left child x Wl, half 1 = right child x Wr
#pragma unroll 1
    for (int half = 0; half < 2; ++half) {
        const float* __restrict__ Bp = (half ? Wr : Wl) + 2 * t;
        const float* Ab = A + half * 128;
#pragma unroll 1
        for (int kb = 0; kb < 128; kb += 4) {
            float4 a[16];
#pragma unroll
            for (int m = 0; m < 16; ++m) a[m] = *(const float4*)(Ab + (m << 8) + kb);
            float2 b[4];
#pragma unroll
            for (int u = 0; u < 4; ++u) b[u] = *(const float2*)(Bp + (kb + u) * 640);
#pragma unroll
            for (int u = 0; u < 4; ++u) {
#pragma unroll
                for (int m = 0; m < 16; ++m) {
                    float av = (&a[m].x)[u];
                    acc0[m] = fmaf(av, b[u].x, acc0[m]);
                    acc1[m] = fmaf(av, b[u].y, acc1[m]);
                }
            }
        }
    }

    // epilogue in 4-row chunks through CH
    for (int c0 = 0; c0 < 16; c0 += 4) {
        __syncthreads();
#pragma unroll
        for (int m = 0; m < 4; ++m) {
            float2 s2; s2.x = acc0[c0 + m]; s2.y = acc1[c0 + m];
            *(float2*)(CH + m * 640 + 2 * t) = s2;
        }
        __syncthreads();
        for (int it = t; it < 4 * 128; it += 320) {
            int mm = it >> 7;
            int m = c0 + mm;
            if (m < rows) {
                int i = it & 127;
                const float* Sm = CH + mm * 640;
                int refl = meta[m].z, refr = meta[m].w;
                float cl = ((refl & LEAF_BIT) ? leafC : cInt)[(refl & REF_MASK) * 128 + i];
                float cr = ((refr & LEAF_BIT) ? leafC : cInt)[(refr & REF_MASK) * 128 + i];
                float c = sigm(Sm[i]) * tanhf(Sm[512 + i])
                        + sigm(Sm[128 + i]) * cl
                        + sigm(Sm[256 + i]) * cr;
                float h = sigm(Sm[384 + i]) * tanhf(c);
                int dst = meta[m].x;
                cInt[dst * 128 + i] = c;
                hInt[dst * 128 + i] = h;
            }
        }
    }
}

// ---------------- final gather: out[b,s,:] = h_root[input[b,s]] ----------------
__global__ void gather_kernel(const int* __restrict__ input,
                              const int* __restrict__ rootSlot,
                              const float* __restrict__ hInt,
                              float* __restrict__ out) {
    int idx = blockIdx.x * 256 + threadIdx.x;   // < OUTN
    int token = input[idx >> 7];
    int d = idx & 127;
    out[idx] = hInt[rootSlot[token] * 128 + d];
}

extern "C" void kernel_launch(void* const* d_in, const int* in_sizes, int n_in,
                              void* d_out, int out_size, void* d_ws, size_t ws_size,
                              hipStream_t stream) {
    const int*   input    = (const int*)d_in[0];
    const int*   node_ids = (const int*)d_in[1];
    const int*   left     = (const int*)d_in[2];
    const int*   right    = (const int*)d_in[3];
    const int*   last     = (const int*)d_in[4];
    const float* emb      = (const float*)d_in[5];
    const float* Wl       = (const float*)d_in[6];
    const float* Wlb      = (const float*)d_in[7];
    const float* Wr       = (const float*)d_in[8];
    const float* Wrb      = (const float*)d_in[9];
    float* out = (float*)d_out;

    char* ws = (char*)d_ws;
    int*   counts   = (int*)(ws + OFF_COUNTS);
    int*   rootSlot = (int*)(ws + OFF_ROOT);
    int4*  lists    = (int4*)(ws + OFF_LISTS);
    float* leafH    = (float*)(ws + OFF_LEAFH);
    float* leafC    = (float*)(ws + OFF_LEAFC);
    float* hInt     = (float*)(ws + OFF_HINT);
    float* cInt     = (float*)(ws + OFF_CINT);

    hipMemsetAsync(counts, 0, 8 * sizeof(int), stream);

    leaf_kernel<<<SCV, 128, 0, stream>>>(emb, leafH, leafC);
    meta_kernel<<<(V + MT - 1) / MT, MT, 0, stream>>>(node_ids, left, right, last,
                                                      counts, rootSlot, lists);

    static const int listOffH[7] = {0, 80000, 120000, 160000, 180000, 200000, 220000};
    static const int capsH[7]    = {80000, 40000, 40000, 20000, 20000, 20000, 20000};
    for (int h = 1; h <= 7; ++h) {
        int blocks = capsH[h - 1] / 16;
        node_gemm<<<blocks, 320, 0, stream>>>(lists + listOffH[h - 1], counts + h,
                                              emb, Wl, Wlb, Wr, Wrb,
                                              leafH, leafC, hInt, cInt);
    }

    gather_kernel<<<OUTN / 256, 256, 0, stream>>>(input, rootSlot, hInt, out);
}

// Round 4
// 726.509 us; speedup vs baseline: 2.2615x; 1.0921x over previous
//
#include <hip/hip_runtime.h>
#include <math.h>

// Problem constants
#define V    20000
#define SCV  4000
#define DD   128
#define LL   15
#define OUTN (16384 * 128)   // B*S*D

#define LEAF_BIT 0x40000000
#define REF_MASK 0x3FFFFFFF

// ---- workspace layout (bytes) ----
// counts:   int[32]           @ 0        (0..18 = bin counts, 31 = slot allocator)
// rootSlot: int[V]            @ 128
// lists:    int4[560000]      @ 80384
// leafH:    float[4000*128]   @ 9040384
// leafC:    float[4000*128]   @ 11088384
// LT:       float[4000*640]   @ 13136384
// RT:       float[4000*640]   @ 23376384
// hInt:     float[90000*128]  @ 33616384
// cInt:     float[90000*128]  @ 79696384
// total 125,776,384 B
#define OFF_COUNTS 0
#define OFF_ROOT   128
#define OFF_LISTS  80384
#define OFF_LEAFH  9040384
#define OFF_LEAFC  11088384
#define OFF_LT     13136384
#define OFF_RT     23376384
#define OFF_HINT   33616384
#define OFF_CINT   79696384

// bins: 0 = h1 (both leaves); for h in 2..7: 1+(h-2)*3 + {0:int-leaf, 1:leaf-int, 2:int-int}
__device__ __constant__ int d_binOff[19] = {
    0,
    80000, 120000, 160000,     // h2
    200000, 240000, 280000,    // h3
    320000, 340000, 360000,    // h4
    380000, 400000, 420000,    // h5
    440000, 460000, 480000,    // h6
    500000, 520000, 540000     // h7
};

__device__ __forceinline__ float sigm(float x) { return 1.0f / (1.0f + expf(-x)); }

// ---------------- leaf kernel: per sub-char-id leaf (h,c) ----------------
__global__ void leaf_kernel(const float* __restrict__ emb,
                            float* __restrict__ leafH, float* __restrict__ leafC) {
    int row = blockIdx.x;       // 0..SCV-1
    int i   = threadIdx.x;      // 0..127
    const float* e = emb + row * 640;
    float ig = e[i];
    float og = e[384 + i];
    float ug = e[512 + i];
    float c = sigm(ig) * tanhf(ug);
    float h = sigm(og) * tanhf(c);
    leafH[row * 128 + i] = h;
    leafC[row * 128 + i] = c;
}

// ---------------- table kernel: LT = leafH@Wl + Wlb, RT = leafH@Wr + Wrb ----------------
__launch_bounds__(320)
__global__ void table_kernel(const float* __restrict__ leafH,
                             const float* __restrict__ Wl, const float* __restrict__ Wlb,
                             const float* __restrict__ Wr, const float* __restrict__ Wrb,
                             float* __restrict__ LT, float* __restrict__ RT) {
    __shared__ float A[16 * 128];
    int which = blockIdx.y;
    const float* W  = which ? Wr : Wl;
    const float* Wb = which ? Wrb : Wlb;
    float* OUT      = which ? RT : LT;
    int r0 = blockIdx.x * 16;
    int t = threadIdx.x;
    for (int idx = t; idx < 16 * 128; idx += 320) A[idx] = leafH[r0 * 128 + idx];
    float acc0[16], acc1[16];
    float b0 = Wb[2 * t], b1 = Wb[2 * t + 1];
#pragma unroll
    for (int m = 0; m < 16; ++m) { acc0[m] = b0; acc1[m] = b1; }
    __syncthreads();
    const float* Bp = W + 2 * t;
#pragma unroll 1
    for (int kb = 0; kb < 128; kb += 4) {
        float4 a[16];
#pragma unroll
        for (int m = 0; m < 16; ++m) a[m] = *(const float4*)(A + (m << 7) + kb);
        float2 bb[4];
#pragma unroll
        for (int u = 0; u < 4; ++u) bb[u] = *(const float2*)(Bp + (kb + u) * 640);
#pragma unroll
        for (int u = 0; u < 4; ++u)
#pragma unroll
            for (int m = 0; m < 16; ++m) {
                float av = (&a[m].x)[u];
                acc0[m] = fmaf(av, bb[u].x, acc0[m]);
                acc1[m] = fmaf(av, bb[u].y, acc1[m]);
            }
    }
#pragma unroll
    for (int m = 0; m < 16; ++m)
        *(float2*)(OUT + (r0 + m) * 640 + 2 * t) = make_float2(acc0[m], acc1[m]);
}

// ---------------- metadata: heights, patterns, compact slots, work lists ----------------
#define MT 128
__global__ void meta_kernel(const int* __restrict__ node_ids,
                            const int* __restrict__ left,
                            const int* __restrict__ right,
                            const int* __restrict__ last,
                            int* __restrict__ counts,
                            int* __restrict__ rootSlot,
                            int4* __restrict__ lists) {
    __shared__ int  sHei[MT][17];
    __shared__ int  sRef[MT][17];
    __shared__ int4 ebuf[MT][7];
    __shared__ int  ebin[MT][7];
    __shared__ int  locCnt[19];
    __shared__ int  basePos[19];
    __shared__ int  scanBuf[MT];
    __shared__ int  blockBase;

    int tid = threadIdx.x;
    if (tid < 19) locCnt[tid] = 0;
    __syncthreads();

    int v = blockIdx.x * MT + tid;
    int nInt = 0;
    if (v < V) {
        int l15[LL], r15[LL], id15[LL];
#pragma unroll
        for (int j = 0; j < LL; ++j) {
            l15[j]  = left[v * LL + j];
            r15[j]  = right[v * LL + j];
            id15[j] = node_ids[v * LL + j];
        }
        int lastv = last[v];
#pragma unroll
        for (int j = 0; j < LL; ++j) {
            if (j <= lastv) {
                int l = l15[j];
                if (l < 0) {
                    sHei[tid][j] = 0;
                    sRef[tid][j] = LEAF_BIT | id15[j];
                } else {
                    int r = r15[j];
                    int hl = sHei[tid][l], hr = sHei[tid][r];
                    int hh = 1 + (hl > hr ? hl : hr);
                    sHei[tid][j] = hh;
                    int rl = sRef[tid][l], rr = sRef[tid][r];
                    int lLeaf = (rl >> 30) & 1, rLeaf = (rr >> 30) & 1;
                    int bin; int4 e;
                    e.x = nInt; e.y = id15[j];
                    if (hh == 1)              { bin = 0;                    e.z = rl; e.w = rr; }
                    else if (!lLeaf && rLeaf) { bin = 1 + (hh - 2) * 3;     e.z = rl; e.w = rr; }
                    else if (lLeaf && !rLeaf) { bin = 1 + (hh - 2) * 3 + 1; e.z = rr; e.w = rl; } // (intSlot, leafId)
                    else                      { bin = 1 + (hh - 2) * 3 + 2; e.z = rl; e.w = rr; }
                    int pos = atomicAdd(&locCnt[bin], 1);
                    ebuf[tid][nInt] = e;
                    ebin[tid][nInt] = (bin << 16) | pos;
                    sRef[tid][j] = nInt;    // local slot index
                    ++nInt;
                }
            }
        }
    }
    // block-level inclusive scan of nInt -> compact slot bases
    scanBuf[tid] = nInt;
    __syncthreads();
    for (int d = 1; d < MT; d <<= 1) {
        int val = (tid >= d) ? scanBuf[tid - d] : 0;
        __syncthreads();
        scanBuf[tid] += val;
        __syncthreads();
    }
    if (tid == 0) blockBase = atomicAdd(&counts[31], scanBuf[MT - 1]);
    if (tid < 19) {
        int c = locCnt[tid];
        basePos[tid] = c ? atomicAdd(&counts[tid], c) : 0;
    }
    __syncthreads();
    int treeBase = blockBase + scanBuf[tid] - nInt;
    if (v < V) rootSlot[v] = treeBase + nInt - 1;
    for (int e = 0; e < nInt; ++e) {
        int4 E  = ebuf[tid][e];
        int md  = ebin[tid][e];
        int bin = md >> 16, pos = md & 0xFFFF;
        E.x += treeBase;
        E.z = (E.z & LEAF_BIT) ? (E.z & REF_MASK) : (E.z + treeBase);
        E.w = (E.w & LEAF_BIT) ? (E.w & REF_MASK) : (E.w + treeBase);
        lists[d_binOff[bin] + basePos[bin] + pos] = E;
    }
}

// ---------------- h1: both children leaves -> pure table gather-add ----------------
__global__ void h1_kernel(const int4* __restrict__ list, const int* __restrict__ cntPtr,
                          const float* __restrict__ emb,
                          const float* __restrict__ LT, const float* __restrict__ RT,
                          const float* __restrict__ leafC,
                          float* __restrict__ hInt, float* __restrict__ cInt) {
    int cnt = *cntPtr;
    int n = blockIdx.x * 4 + (threadIdx.x >> 7);
    if (n >= cnt) return;
    int i = threadIdx.x & 127;
    int4 E = list[n];                       // (dst, id, lid, rid)
    const float* e  = emb + E.y * 640 + i;
    const float* lt = LT  + E.z * 640 + i;
    const float* rt = RT  + E.w * 640 + i;
    float s0 = e[0]   + lt[0]   + rt[0];
    float s1 = e[128] + lt[128] + rt[128];
    float s2 = e[256] + lt[256] + rt[256];
    float s3 = e[384] + lt[384] + rt[384];
    float s4 = e[512] + lt[512] + rt[512];
    float cl = leafC[E.z * 128 + i], cr = leafC[E.w * 128 + i];
    float c = sigm(s0) * tanhf(s4) + sigm(s1) * cl + sigm(s2) * cr;
    float h = sigm(s3) * tanhf(c);
    cInt[E.x * 128 + i] = c;
    hInt[E.x * 128 + i] = h;
}

// ---------------- gathered GEMMs for height rounds ----------------
// one internal child: K=128, leaf side from table. entry = (dst, id, intSlot, leafId)
__device__ void gemm_one(const int4* __restrict__ list, const int* __restrict__ cntPtr, int blk,
                         const float* __restrict__ W, const float* __restrict__ Wb,
                         const float* __restrict__ tab, bool intLeft,
                         const float* __restrict__ emb, const float* __restrict__ leafC,
                         float* __restrict__ hInt, float* __restrict__ cInt,
                         float* A, float* CH, int4* meta) {
    int cnt = *cntPtr;
    int base = blk * 16;
    if (base >= cnt) return;
    int rows = cnt - base; if (rows > 16) rows = 16;
    int t = threadIdx.x;
    if (t < 16) meta[t] = list[base + (t < rows ? t : 0)];
    __syncthreads();
    for (int idx = t; idx < 16 * 128; idx += 320) {
        int m = idx >> 7, k = idx & 127;
        A[idx] = hInt[meta[m].z * 128 + k];
    }
    float b0 = Wb[2 * t], b1 = Wb[2 * t + 1];
    float acc0[16], acc1[16];
#pragma unroll
    for (int m = 0; m < 16; ++m) {
        const float* e  = emb + meta[m].y * 640;
        const float* tb = tab + meta[m].w * 640;
        acc0[m] = e[2 * t]     + tb[2 * t]     + b0;
        acc1[m] = e[2 * t + 1] + tb[2 * t + 1] + b1;
    }
    __syncthreads();
    const float* Bp = W + 2 * t;
#pragma unroll 1
    for (int kb = 0; kb < 128; kb += 4) {
        float4 a[16];
#pragma unroll
        for (int m = 0; m < 16; ++m) a[m] = *(const float4*)(A + (m << 7) + kb);
        float2 bb[4];
#pragma unroll
        for (int u = 0; u < 4; ++u) bb[u] = *(const float2*)(Bp + (kb + u) * 640);
#pragma unroll
        for (int u = 0; u < 4; ++u)
#pragma unroll
            for (int m = 0; m < 16; ++m) {
                float av = (&a[m].x)[u];
                acc0[m] = fmaf(av, bb[u].x, acc0[m]);
                acc1[m] = fmaf(av, bb[u].y, acc1[m]);
            }
    }
    for (int c0 = 0; c0 < 16; c0 += 4) {
        __syncthreads();
#pragma unroll
        for (int m = 0; m < 4; ++m)
            *(float2*)(CH + m * 640 + 2 * t) = make_float2(acc0[c0 + m], acc1[c0 + m]);
        __syncthreads();
        for (int it = t; it < 4 * 128; it += 320) {
            int mm = it >> 7, m = c0 + mm;
            if (m < rows) {
                int i = it & 127;
                const float* Sm = CH + mm * 640;
                float cI = cInt[meta[m].z * 128 + i];
                float cL = leafC[meta[m].w * 128 + i];
                float cl = intLeft ? cI : cL;
                float cr = intLeft ? cL : cI;
                float c = sigm(Sm[i]) * tanhf(Sm[512 + i])
                        + sigm(Sm[128 + i]) * cl + sigm(Sm[256 + i]) * cr;
                float h = sigm(Sm[384 + i]) * tanhf(c);
                int dst = meta[m].x;
                cInt[dst * 128 + i] = c;
                hInt[dst * 128 + i] = h;
            }
        }
    }
}

// two internal children: K=256. entry = (dst, id, lslot, rslot)
__device__ void gemm_two(const int4* __restrict__ list, const int* __restrict__ cntPtr, int blk,
                         const float* __restrict__ Wl, const float* __restrict__ Wlb,
                         const float* __restrict__ Wr, const float* __restrict__ Wrb,
                         const float* __restrict__ emb,
                         float* __restrict__ hInt, float* __restrict__ cInt,
                         float* A, float* CH, int4* meta) {
    int cnt = *cntPtr;
    int base = blk * 16;
    if (base >= cnt) return;
    int rows = cnt - base; if (rows > 16) rows = 16;
    int t = threadIdx.x;
    if (t < 16) meta[t] = list[base + (t < rows ? t : 0)];
    __syncthreads();
    for (int idx = t; idx < 16 * 256; idx += 320) {
        int m = idx >> 8, k = idx & 255;
        int ref = (k < 128) ? meta[m].z : meta[m].w;
        A[idx] = hInt[ref * 128 + (k & 127)];
    }
    float b0 = Wlb[2 * t] + Wrb[2 * t], b1 = Wlb[2 * t + 1] + Wrb[2 * t + 1];
    float acc0[16], acc1[16];
#pragma unroll
    for (int m = 0; m < 16; ++m) {
        const float* e = emb + meta[m].y * 640;
        acc0[m] = e[2 * t] + b0;
        acc1[m] = e[2 * t + 1] + b1;
    }
    __syncthreads();
#pragma unroll 1
    for (int half = 0; half < 2; ++half) {
        const float* Bp = (half ? Wr : Wl) + 2 * t;
        const float* Ab = A + half * 128;
#pragma unroll 1
        for (int kb = 0; kb < 128; kb += 4) {
            float4 a[16];
#pragma unroll
            for (int m = 0; m < 16; ++m) a[m] = *(const float4*)(Ab + (m << 8) + kb);
            float2 bb[4];
#pragma unroll
            for (int u = 0; u < 4; ++u) bb[u] = *(const float2*)(Bp + (kb + u) * 640);
#pragma unroll
            for (int u = 0; u < 4; ++u)
#pragma unroll
                for (int m = 0; m < 16; ++m) {
                    float av = (&a[m].x)[u];
                    acc0[m] = fmaf(av, bb[u].x, acc0[m]);
                    acc1[m] = fmaf(av, bb[u].y, acc1[m]);
                }
        }
    }
    for (int c0 = 0; c0 < 16; c0 += 4) {
        __syncthreads();
#pragma unroll
        for (int m = 0; m < 4; ++m)
            *(float2*)(CH + m * 640 + 2 * t) = make_float2(acc0[c0 + m], acc1[c0 + m]);
        __syncthreads();
        for (int it = t; it < 4 * 128; it += 320) {
            int mm = it >> 7, m = c0 + mm;
            if (m < rows) {
                int i = it & 127;
                const float* Sm = CH + mm * 640;
                float cl = cInt[meta[m].z * 128 + i];
                float cr = cInt[meta[m].w * 128 + i];
                float c = sigm(Sm[i]) * tanhf(Sm[512 + i])
                        + sigm(Sm[128 + i]) * cl + sigm(Sm[256 + i]) * cr;
                float h = sigm(Sm[384 + i]) * tanhf(c);
                int dst = meta[m].x;
                cInt[dst * 128 + i] = c;
                hInt[dst * 128 + i] = h;
            }
        }
    }
}

__launch_bounds__(320)
__global__ void round_kernel(const int4* __restrict__ l1, const int* __restrict__ c1, int NB1,
                             const int4* __restrict__ l2, const int* __restrict__ c2, int NB2,
                             const int4* __restrict__ l3, const int* __restrict__ c3,
                             const float* __restrict__ emb,
                             const float* __restrict__ Wl, const float* __restrict__ Wlb,
                             const float* __restrict__ Wr, const float* __restrict__ Wrb,
                             const float* __restrict__ LT, const float* __restrict__ RT,
                             const float* __restrict__ leafC,
                             float* __restrict__ hInt, float* __restrict__ cInt) {
    __shared__ float A[16 * 256];
    __shared__ float CH[4 * 640];
    __shared__ int4  meta[16];
    int b = blockIdx.x;
    if (b < NB1)
        gemm_one(l1, c1, b, Wl, Wlb, RT, true, emb, leafC, hInt, cInt, A, CH, meta);
    else if (b < NB1 + NB2)
        gemm_one(l2, c2, b - NB1, Wr, Wrb, LT, false, emb, leafC, hInt, cInt, A, CH, meta);
    else
        gemm_two(l3, c3, b - NB1 - NB2, Wl, Wlb, Wr, Wrb, emb, hInt, cInt, A, CH, meta);
}

// ---------------- final gather: out[b,s,:] = h_root[input[b,s]] ----------------
__global__ void gather_kernel(const int* __restrict__ input,
                              const int* __restrict__ rootSlot,
                              const float* __restrict__ hInt,
                              float4* __restrict__ out) {
    int idx = blockIdx.x * 256 + threadIdx.x;   // < OUTN/4
    int token = input[idx >> 5];
    int d = idx & 31;
    out[idx] = ((const float4*)hInt)[rootSlot[token] * 32 + d];
}

extern "C" void kernel_launch(void* const* d_in, const int* in_sizes, int n_in,
                              void* d_out, int out_size, void* d_ws, size_t ws_size,
                              hipStream_t stream) {
    const int*   input    = (const int*)d_in[0];
    const int*   node_ids = (const int*)d_in[1];
    const int*   left     = (const int*)d_in[2];
    const int*   right    = (const int*)d_in[3];
    const int*   last     = (const int*)d_in[4];
    const float* emb      = (const float*)d_in[5];
    const float* Wl       = (const float*)d_in[6];
    const float* Wlb      = (const float*)d_in[7];
    const float* Wr       = (const float*)d_in[8];
    const float* Wrb      = (const float*)d_in[9];
    float* out = (float*)d_out;

    char* ws = (char*)d_ws;
    int*   counts   = (int*)(ws + OFF_COUNTS);
    int*   rootSlot = (int*)(ws + OFF_ROOT);
    int4*  lists    = (int4*)(ws + OFF_LISTS);
    float* leafH    = (float*)(ws + OFF_LEAFH);
    float* leafC    = (float*)(ws + OFF_LEAFC);
    float* LTp      = (float*)(ws + OFF_LT);
    float* RTp      = (float*)(ws + OFF_RT);
    float* hInt     = (float*)(ws + OFF_HINT);
    float* cInt     = (float*)(ws + OFF_CINT);

    (void)hipMemsetAsync(counts, 0, 128, stream);

    leaf_kernel<<<SCV, 128, 0, stream>>>(emb, leafH, leafC);
    table_kernel<<<dim3(SCV / 16, 2), 320, 0, stream>>>(leafH, Wl, Wlb, Wr, Wrb, LTp, RTp);
    meta_kernel<<<(V + MT - 1) / MT, MT, 0, stream>>>(node_ids, left, right, last,
                                                      counts, rootSlot, lists);

    h1_kernel<<<20000, 512, 0, stream>>>(lists, counts, emb, LTp, RTp, leafC, hInt, cInt);

    static const int binOffH[19] = {
        0,
        80000, 120000, 160000,
        200000, 240000, 280000,
        320000, 340000, 360000,
        380000, 400000, 420000,
        440000, 460000, 480000,
        500000, 520000, 540000
    };
    for (int h = 2; h <= 7; ++h) {
        int bi   = 1 + (h - 2) * 3;
        int cap  = (h <= 3) ? 40000 : 20000;
        int NB   = cap / 16;
        round_kernel<<<3 * NB, 320, 0, stream>>>(
            lists + binOffH[bi],     counts + bi,     NB,
            lists + binOffH[bi + 1], counts + bi + 1, NB,
            lists + binOffH[bi + 2], counts + bi + 2,
            emb, Wl, Wlb, Wr, Wrb, LTp, RTp, leafC, hInt, cInt);
    }

    gather_kernel<<<OUTN / 4 / 256, 256, 0, stream>>>(input, rootSlot, hInt, (float4*)out);
}

// Round 5
// 704.706 us; speedup vs baseline: 2.3314x; 1.0309x over previous
//
#include <hip/hip_runtime.h>
#include <math.h>

// Problem constants
#define V    20000
#define SCV  4000
#define DD   128
#define LL   15
#define OUTN (16384 * 128)   // B*S*D

#define LEAF_BIT 0x40000000
#define REF_MASK 0x3FFFFFFF

// ---- workspace layout (bytes) ----
#define OFF_COUNTS 0
#define OFF_ROOT   128
#define OFF_LISTS  80384
#define OFF_LEAFH  9040384
#define OFF_LEAFC  11088384
#define OFF_LT     13136384
#define OFF_RT     23376384
#define OFF_HINT   33616384
#define OFF_CINT   79696384

// bins: 0 = h1 (both leaves); for h in 2..7: 1+(h-2)*3 + {0:int-leaf, 1:leaf-int, 2:int-int}
__device__ __constant__ int d_binOff[19] = {
    0,
    80000, 120000, 160000,     // h2
    200000, 240000, 280000,    // h3
    320000, 340000, 360000,    // h4
    380000, 400000, 420000,    // h5
    440000, 460000, 480000,    // h6
    500000, 520000, 540000     // h7
};

#define ROUND_BLOCKS 2560
#define H1_BLOCKS    2560

__device__ __forceinline__ float sigm(float x) { return 1.0f / (1.0f + expf(-x)); }

// ---------------- leaf kernel: per sub-char-id leaf (h,c) ----------------
__global__ void leaf_kernel(const float* __restrict__ emb,
                            float* __restrict__ leafH, float* __restrict__ leafC) {
    int row = blockIdx.x;       // 0..SCV-1
    int i   = threadIdx.x;      // 0..127
    const float* e = emb + row * 640;
    float ig = e[i];
    float og = e[384 + i];
    float ug = e[512 + i];
    float c = sigm(ig) * tanhf(ug);
    float h = sigm(og) * tanhf(c);
    leafH[row * 128 + i] = h;
    leafC[row * 128 + i] = c;
}

// ---------------- table kernel: LT = leafH@Wl + Wlb, RT = leafH@Wr + Wrb ----------------
__launch_bounds__(320)
__global__ void table_kernel(const float* __restrict__ leafH,
                             const float* __restrict__ Wl, const float* __restrict__ Wlb,
                             const float* __restrict__ Wr, const float* __restrict__ Wrb,
                             float* __restrict__ LT, float* __restrict__ RT) {
    __shared__ float A[16 * 128];
    int which = blockIdx.y;
    const float* W  = which ? Wr : Wl;
    const float* Wb = which ? Wrb : Wlb;
    float* OUT      = which ? RT : LT;
    int r0 = blockIdx.x * 16;
    int t = threadIdx.x;
    for (int idx = t; idx < 16 * 128; idx += 320) A[idx] = leafH[r0 * 128 + idx];
    float acc0[16], acc1[16];
    float b0 = Wb[2 * t], b1 = Wb[2 * t + 1];
#pragma unroll
    for (int m = 0; m < 16; ++m) { acc0[m] = b0; acc1[m] = b1; }
    __syncthreads();
    const float* Bp = W + 2 * t;
#pragma unroll 1
    for (int kb = 0; kb < 128; kb += 4) {
        float4 a[16];
#pragma unroll
        for (int m = 0; m < 16; ++m) a[m] = *(const float4*)(A + (m << 7) + kb);
        float2 bb[4];
#pragma unroll
        for (int u = 0; u < 4; ++u) bb[u] = *(const float2*)(Bp + (kb + u) * 640);
#pragma unroll
        for (int u = 0; u < 4; ++u)
#pragma unroll
            for (int m = 0; m < 16; ++m) {
                float av = (&a[m].x)[u];
                acc0[m] = fmaf(av, bb[u].x, acc0[m]);
                acc1[m] = fmaf(av, bb[u].y, acc1[m]);
            }
    }
#pragma unroll
    for (int m = 0; m < 16; ++m)
        *(float2*)(OUT + (r0 + m) * 640 + 2 * t) = make_float2(acc0[m], acc1[m]);
}

// ---------------- metadata: heights, patterns, compact slots, work lists ----------------
#define MT 128
__global__ void meta_kernel(const int* __restrict__ node_ids,
                            const int* __restrict__ left,
                            const int* __restrict__ right,
                            const int* __restrict__ last,
                            int* __restrict__ counts,
                            int* __restrict__ rootSlot,
                            int4* __restrict__ lists) {
    __shared__ int  sHei[MT][17];
    __shared__ int  sRef[MT][17];
    __shared__ int4 ebuf[MT][7];
    __shared__ int  ebin[MT][7];
    __shared__ int  locCnt[19];
    __shared__ int  basePos[19];
    __shared__ int  scanBuf[MT];
    __shared__ int  blockBase;

    int tid = threadIdx.x;
    if (tid < 19) locCnt[tid] = 0;
    __syncthreads();

    int v = blockIdx.x * MT + tid;
    int nInt = 0;
    if (v < V) {
        int l15[LL], r15[LL], id15[LL];
#pragma unroll
        for (int j = 0; j < LL; ++j) {
            l15[j]  = left[v * LL + j];
            r15[j]  = right[v * LL + j];
            id15[j] = node_ids[v * LL + j];
        }
        int lastv = last[v];
#pragma unroll
        for (int j = 0; j < LL; ++j) {
            if (j <= lastv) {
                int l = l15[j];
                if (l < 0) {
                    sHei[tid][j] = 0;
                    sRef[tid][j] = LEAF_BIT | id15[j];
                } else {
                    int r = r15[j];
                    int hl = sHei[tid][l], hr = sHei[tid][r];
                    int hh = 1 + (hl > hr ? hl : hr);
                    sHei[tid][j] = hh;
                    int rl = sRef[tid][l], rr = sRef[tid][r];
                    int lLeaf = (rl >> 30) & 1, rLeaf = (rr >> 30) & 1;
                    int bin; int4 e;
                    e.x = nInt; e.y = id15[j];
                    if (hh == 1)              { bin = 0;                    e.z = rl; e.w = rr; }
                    else if (!lLeaf && rLeaf) { bin = 1 + (hh - 2) * 3;     e.z = rl; e.w = rr; }
                    else if (lLeaf && !rLeaf) { bin = 1 + (hh - 2) * 3 + 1; e.z = rr; e.w = rl; } // (intSlot, leafId)
                    else                      { bin = 1 + (hh - 2) * 3 + 2; e.z = rl; e.w = rr; }
                    int pos = atomicAdd(&locCnt[bin], 1);
                    ebuf[tid][nInt] = e;
                    ebin[tid][nInt] = (bin << 16) | pos;
                    sRef[tid][j] = nInt;    // local slot index
                    ++nInt;
                }
            }
        }
    }
    // block-level inclusive scan of nInt -> compact slot bases
    scanBuf[tid] = nInt;
    __syncthreads();
    for (int d = 1; d < MT; d <<= 1) {
        int val = (tid >= d) ? scanBuf[tid - d] : 0;
        __syncthreads();
        scanBuf[tid] += val;
        __syncthreads();
    }
    if (tid == 0) blockBase = atomicAdd(&counts[31], scanBuf[MT - 1]);
    if (tid < 19) {
        int c = locCnt[tid];
        basePos[tid] = c ? atomicAdd(&counts[tid], c) : 0;
    }
    __syncthreads();
    int treeBase = blockBase + scanBuf[tid] - nInt;
    if (v < V) rootSlot[v] = treeBase + nInt - 1;
    for (int e = 0; e < nInt; ++e) {
        int4 E  = ebuf[tid][e];
        int md  = ebin[tid][e];
        int bin = md >> 16, pos = md & 0xFFFF;
        E.x += treeBase;
        E.z = (E.z & LEAF_BIT) ? (E.z & REF_MASK) : (E.z + treeBase);
        E.w = (E.w & LEAF_BIT) ? (E.w & REF_MASK) : (E.w + treeBase);
        lists[d_binOff[bin] + basePos[bin] + pos] = E;
    }
}

// ---------------- h1: both children leaves -> pure table gather-add ----------------
// grid-stride over nodes: no empty-block dispatch waste.
__global__ void h1_kernel(const int4* __restrict__ list, const int* __restrict__ cntPtr,
                          const float* __restrict__ emb,
                          const float* __restrict__ LT, const float* __restrict__ RT,
                          const float* __restrict__ leafC,
                          float* __restrict__ hInt, float* __restrict__ cInt) {
    int cnt = *cntPtr;
    int i = threadIdx.x & 127;
    for (int n = blockIdx.x * 4 + (threadIdx.x >> 7); n < cnt; n += gridDim.x * 4) {
        int4 E = list[n];                       // (dst, id, lid, rid)
        const float* e  = emb + E.y * 640 + i;
        const float* lt = LT  + E.z * 640 + i;
        const float* rt = RT  + E.w * 640 + i;
        float s0 = e[0]   + lt[0]   + rt[0];
        float s1 = e[128] + lt[128] + rt[128];
        float s2 = e[256] + lt[256] + rt[256];
        float s3 = e[384] + lt[384] + rt[384];
        float s4 = e[512] + lt[512] + rt[512];
        float cl = leafC[E.z * 128 + i], cr = leafC[E.w * 128 + i];
        float c = sigm(s0) * tanhf(s4) + sigm(s1) * cl + sigm(s2) * cr;
        float h = sigm(s3) * tanhf(c);
        cInt[E.x * 128 + i] = c;
        hInt[E.x * 128 + i] = h;
    }
}

// ---------------- gathered GEMMs for height rounds ----------------
// one internal child: K=128, leaf side from table. entry = (dst, id, intSlot, leafId)
__device__ void gemm_one(const int4* __restrict__ list, int cnt, int blk,
                         const float* __restrict__ W, const float* __restrict__ Wb,
                         const float* __restrict__ tab, bool intLeft,
                         const float* __restrict__ emb, const float* __restrict__ leafC,
                         float* __restrict__ hInt, float* __restrict__ cInt,
                         float* A, float* CH, int4* meta) {
    int base = blk * 16;
    int rows = cnt - base; if (rows > 16) rows = 16;
    int t = threadIdx.x;
    if (t < 16) meta[t] = list[base + (t < rows ? t : 0)];
    __syncthreads();
    for (int idx = t; idx < 16 * 128; idx += 320) {
        int m = idx >> 7, k = idx & 127;
        A[idx] = hInt[meta[m].z * 128 + k];
    }
    float b0 = Wb[2 * t], b1 = Wb[2 * t + 1];
    float acc0[16], acc1[16];
#pragma unroll
    for (int m = 0; m < 16; ++m) {
        const float* e  = emb + meta[m].y * 640;
        const float* tb = tab + meta[m].w * 640;
        acc0[m] = e[2 * t]     + tb[2 * t]     + b0;
        acc1[m] = e[2 * t + 1] + tb[2 * t + 1] + b1;
    }
    __syncthreads();
    const float* Bp = W + 2 * t;
#pragma unroll 1
    for (int kb = 0; kb < 128; kb += 4) {
        float4 a[16];
#pragma unroll
        for (int m = 0; m < 16; ++m) a[m] = *(const float4*)(A + (m << 7) + kb);
        float2 bb[4];
#pragma unroll
        for (int u = 0; u < 4; ++u) bb[u] = *(const float2*)(Bp + (kb + u) * 640);
#pragma unroll
        for (int u = 0; u < 4; ++u)
#pragma unroll
            for (int m = 0; m < 16; ++m) {
                float av = (&a[m].x)[u];
                acc0[m] = fmaf(av, bb[u].x, acc0[m]);
                acc1[m] = fmaf(av, bb[u].y, acc1[m]);
            }
    }
    for (int c0 = 0; c0 < 16; c0 += 4) {
        __syncthreads();
#pragma unroll
        for (int m = 0; m < 4; ++m)
            *(float2*)(CH + m * 640 + 2 * t) = make_float2(acc0[c0 + m], acc1[c0 + m]);
        __syncthreads();
        for (int it = t; it < 4 * 128; it += 320) {
            int mm = it >> 7, m = c0 + mm;
            if (m < rows) {
                int i = it & 127;
                const float* Sm = CH + mm * 640;
                float cI = cInt[meta[m].z * 128 + i];
                float cL = leafC[meta[m].w * 128 + i];
                float cl = intLeft ? cI : cL;
                float cr = intLeft ? cL : cI;
                float c = sigm(Sm[i]) * tanhf(Sm[512 + i])
                        + sigm(Sm[128 + i]) * cl + sigm(Sm[256 + i]) * cr;
                float h = sigm(Sm[384 + i]) * tanhf(c);
                int dst = meta[m].x;
                cInt[dst * 128 + i] = c;
                hInt[dst * 128 + i] = h;
            }
        }
    }
}

// two internal children: K=256. entry = (dst, id, lslot, rslot)
__device__ void gemm_two(const int4* __restrict__ list, int cnt, int blk,
                         const float* __restrict__ Wl, const float* __restrict__ Wlb,
                         const float* __restrict__ Wr, const float* __restrict__ Wrb,
                         const float* __restrict__ emb,
                         float* __restrict__ hInt, float* __restrict__ cInt,
                         float* A, float* CH, int4* meta) {
    int base = blk * 16;
    int rows = cnt - base; if (rows > 16) rows = 16;
    int t = threadIdx.x;
    if (t < 16) meta[t] = list[base + (t < rows ? t : 0)];
    __syncthreads();
    for (int idx = t; idx < 16 * 256; idx += 320) {
        int m = idx >> 8, k = idx & 255;
        int ref = (k < 128) ? meta[m].z : meta[m].w;
        A[idx] = hInt[ref * 128 + (k & 127)];
    }
    float b0 = Wlb[2 * t] + Wrb[2 * t], b1 = Wlb[2 * t + 1] + Wrb[2 * t + 1];
    float acc0[16], acc1[16];
#pragma unroll
    for (int m = 0; m < 16; ++m) {
        const float* e = emb + meta[m].y * 640;
        acc0[m] = e[2 * t] + b0;
        acc1[m] = e[2 * t + 1] + b1;
    }
    __syncthreads();
#pragma unroll 1
    for (int half = 0; half < 2; ++half) {
        const float* Bp = (half ? Wr : Wl) + 2 * t;
        const float* Ab = A + half * 128;
#pragma unroll 1
        for (int kb = 0; kb < 128; kb += 4) {
            float4 a[16];
#pragma unroll
            for (int m = 0; m < 16; ++m) a[m] = *(const float4*)(Ab + (m << 8) + kb);
            float2 bb[4];
#pragma unroll
            for (int u = 0; u < 4; ++u) bb[u] = *(const float2*)(Bp + (kb + u) * 640);
#pragma unroll
            for (int u = 0; u < 4; ++u)
#pragma unroll
                for (int m = 0; m < 16; ++m) {
                    float av = (&a[m].x)[u];
                    acc0[m] = fmaf(av, bb[u].x, acc0[m]);
                    acc1[m] = fmaf(av, bb[u].y, acc1[m]);
                }
        }
    }
    for (int c0 = 0; c0 < 16; c0 += 4) {
        __syncthreads();
#pragma unroll
        for (int m = 0; m < 4; ++m)
            *(float2*)(CH + m * 640 + 2 * t) = make_float2(acc0[c0 + m], acc1[c0 + m]);
        __syncthreads();
        for (int it = t; it < 4 * 128; it += 320) {
            int mm = it >> 7, m = c0 + mm;
            if (m < rows) {
                int i = it & 127;
                const float* Sm = CH + mm * 640;
                float cl = cInt[meta[m].z * 128 + i];
                float cr = cInt[meta[m].w * 128 + i];
                float c = sigm(Sm[i]) * tanhf(Sm[512 + i])
                        + sigm(Sm[128 + i]) * cl + sigm(Sm[256 + i]) * cr;
                float h = sigm(Sm[384 + i]) * tanhf(c);
                int dst = meta[m].x;
                cInt[dst * 128 + i] = c;
                hInt[dst * 128 + i] = h;
            }
        }
    }
}

// One persistent grid per round; grid-strides over the unified chunk space of
// the round's three bins (16 nodes per chunk). No empty-block dispatch waste.
__launch_bounds__(320)
__global__ void round_kernel(const int4* __restrict__ l1,
                             const int4* __restrict__ l2,
                             const int4* __restrict__ l3,
                             const int* __restrict__ counts, int bi,
                             const float* __restrict__ emb,
                             const float* __restrict__ Wl, const float* __restrict__ Wlb,
                             const float* __restrict__ Wr, const float* __restrict__ Wrb,
                             const float* __restrict__ LT, const float* __restrict__ RT,
                             const float* __restrict__ leafC,
                             float* __restrict__ hInt, float* __restrict__ cInt) {
    __shared__ float A[16 * 256];
    __shared__ float CH[4 * 640];
    __shared__ int4  meta[16];
    int c1 = counts[bi], c2 = counts[bi + 1], c3 = counts[bi + 2];
    int nb1 = (c1 + 15) >> 4, nb2 = (c2 + 15) >> 4, nb3 = (c3 + 15) >> 4;
    int total = nb1 + nb2 + nb3;
    for (int chunk = blockIdx.x; chunk < total; chunk += gridDim.x) {
        if (chunk < nb1)
            gemm_one(l1, c1, chunk, Wl, Wlb, RT, true, emb, leafC, hInt, cInt, A, CH, meta);
        else if (chunk < nb1 + nb2)
            gemm_one(l2, c2, chunk - nb1, Wr, Wrb, LT, false, emb, leafC, hInt, cInt, A, CH, meta);
        else
            gemm_two(l3, c3, chunk - nb1 - nb2, Wl, Wlb, Wr, Wrb, emb, hInt, cInt, A, CH, meta);
        __syncthreads();   // protect meta/A/CH reuse across chunks
    }
}

// ---------------- final gather: out[b,s,:] = h_root[input[b,s]] ----------------
__global__ void gather_kernel(const int* __restrict__ input,
                              const int* __restrict__ rootSlot,
                              const float* __restrict__ hInt,
                              float4* __restrict__ out) {
    int idx = blockIdx.x * 256 + threadIdx.x;   // < OUTN/4
    int token = input[idx >> 5];
    int d = idx & 31;
    out[idx] = ((const float4*)hInt)[rootSlot[token] * 32 + d];
}

extern "C" void kernel_launch(void* const* d_in, const int* in_sizes, int n_in,
                              void* d_out, int out_size, void* d_ws, size_t ws_size,
                              hipStream_t stream) {
    const int*   input    = (const int*)d_in[0];
    const int*   node_ids = (const int*)d_in[1];
    const int*   left     = (const int*)d_in[2];
    const int*   right    = (const int*)d_in[3];
    const int*   last     = (const int*)d_in[4];
    const float* emb      = (const float*)d_in[5];
    const float* Wl       = (const float*)d_in[6];
    const float* Wlb      = (const float*)d_in[7];
    const float* Wr       = (const float*)d_in[8];
    const float* Wrb      = (const float*)d_in[9];
    float* out = (float*)d_out;

    char* ws = (char*)d_ws;
    int*   counts   = (int*)(ws + OFF_COUNTS);
    int*   rootSlot = (int*)(ws + OFF_ROOT);
    int4*  lists    = (int4*)(ws + OFF_LISTS);
    float* leafH    = (float*)(ws + OFF_LEAFH);
    float* leafC    = (float*)(ws + OFF_LEAFC);
    float* LTp      = (float*)(ws + OFF_LT);
    float* RTp      = (float*)(ws + OFF_RT);
    float* hInt     = (float*)(ws + OFF_HINT);
    float* cInt     = (float*)(ws + OFF_CINT);

    (void)hipMemsetAsync(counts, 0, 128, stream);

    leaf_kernel<<<SCV, 128, 0, stream>>>(emb, leafH, leafC);
    table_kernel<<<dim3(SCV / 16, 2), 320, 0, stream>>>(leafH, Wl, Wlb, Wr, Wrb, LTp, RTp);
    meta_kernel<<<(V + MT - 1) / MT, MT, 0, stream>>>(node_ids, left, right, last,
                                                      counts, rootSlot, lists);

    h1_kernel<<<H1_BLOCKS, 512, 0, stream>>>(lists, counts, emb, LTp, RTp, leafC, hInt, cInt);

    static const int binOffH[19] = {
        0,
        80000, 120000, 160000,
        200000, 240000, 280000,
        320000, 340000, 360000,
        380000, 400000, 420000,
        440000, 460000, 480000,
        500000, 520000, 540000
    };
    for (int h = 2; h <= 7; ++h) {
        int bi = 1 + (h - 2) * 3;
        round_kernel<<<ROUND_BLOCKS, 320, 0, stream>>>(
            lists + binOffH[bi], lists + binOffH[bi + 1], lists + binOffH[bi + 2],
            counts, bi,
            emb, Wl, Wlb, Wr, Wrb, LTp, RTp, leafC, hInt, cInt);
    }

    gather_kernel<<<OUTN / 4 / 256, 256, 0, stream>>>(input, rootSlot, hInt, (float4*)out);
}

// Round 6
// 478.605 us; speedup vs baseline: 3.4328x; 1.4724x over previous
//
#include <hip/hip_runtime.h>
#include <hip/hip_fp16.h>
#include <math.h>

// Problem constants
#define V    20000
#define SCV  4000
#define DD   128
#define LL   15
#define OUTN (16384 * 128)   // B*S*D

#define LEAF_BIT 0x40000000
#define REF_MASK 0x3FFFFFFF

// ---- workspace layout (bytes) ----
#define OFF_COUNTS 0
#define OFF_ROOT   128
#define OFF_LISTS  80384
#define OFF_LEAFH  9040384
#define OFF_LEAFC  11088384
#define OFF_LT     13136384     // fp16 4000x640 = 5.12 MB
#define OFF_RT     23376384     // fp16 4000x640 = 5.12 MB
#define OFF_HINT   33616384
#define OFF_CINT   79696384

// bins: 0 = h1 (both leaves); for h in 2..7: 1+(h-2)*3 + {0:int-leaf, 1:leaf-int, 2:int-int}
__device__ __constant__ int d_binOff[19] = {
    0,
    80000, 120000, 160000,     // h2
    200000, 240000, 280000,    // h3
    320000, 340000, 360000,    // h4
    380000, 400000, 420000,    // h5
    440000, 460000, 480000,    // h6
    500000, 520000, 540000     // h7
};

#define ROUND_BLOCKS 2560
#define H1_BLOCKS    1920

__device__ __forceinline__ float sigm(float x) { return 1.0f / (1.0f + expf(-x)); }

// ---------------- leaf kernel: per sub-char-id leaf (h,c) ----------------
__global__ void leaf_kernel(const float* __restrict__ emb,
                            float* __restrict__ leafH, float* __restrict__ leafC) {
    int row = blockIdx.x;       // 0..SCV-1
    int i   = threadIdx.x;      // 0..127
    const float* e = emb + row * 640;
    float ig = e[i];
    float og = e[384 + i];
    float ug = e[512 + i];
    float c = sigm(ig) * tanhf(ug);
    float h = sigm(og) * tanhf(c);
    leafH[row * 128 + i] = h;
    leafC[row * 128 + i] = c;
}

// ---------------- table kernel: LT = fp16(leafH@Wl + Wlb), RT = fp16(leafH@Wr + Wrb) ----------------
__launch_bounds__(320)
__global__ void table_kernel(const float* __restrict__ leafH,
                             const float* __restrict__ Wl, const float* __restrict__ Wlb,
                             const float* __restrict__ Wr, const float* __restrict__ Wrb,
                             __half* __restrict__ LT, __half* __restrict__ RT) {
    __shared__ float A[16 * 128];
    int which = blockIdx.y;
    const float* W  = which ? Wr : Wl;
    const float* Wb = which ? Wrb : Wlb;
    __half* OUT     = which ? RT : LT;
    int r0 = blockIdx.x * 16;
    int t = threadIdx.x;
    for (int idx = t; idx < 16 * 128; idx += 320) A[idx] = leafH[r0 * 128 + idx];
    float acc0[16], acc1[16];
    float b0 = Wb[2 * t], b1 = Wb[2 * t + 1];
#pragma unroll
    for (int m = 0; m < 16; ++m) { acc0[m] = b0; acc1[m] = b1; }
    __syncthreads();
    const float* Bp = W + 2 * t;
#pragma unroll 1
    for (int kb = 0; kb < 128; kb += 4) {
        float4 a[16];
#pragma unroll
        for (int m = 0; m < 16; ++m) a[m] = *(const float4*)(A + (m << 7) + kb);
        float2 bb[4];
#pragma unroll
        for (int u = 0; u < 4; ++u) bb[u] = *(const float2*)(Bp + (kb + u) * 640);
#pragma unroll
        for (int u = 0; u < 4; ++u)
#pragma unroll
            for (int m = 0; m < 16; ++m) {
                float av = (&a[m].x)[u];
                acc0[m] = fmaf(av, bb[u].x, acc0[m]);
                acc1[m] = fmaf(av, bb[u].y, acc1[m]);
            }
    }
#pragma unroll
    for (int m = 0; m < 16; ++m)
        ((__half2*)OUT)[(r0 + m) * 320 + t] = __float22half2_rn(make_float2(acc0[m], acc1[m]));
}

// ---------------- metadata: heights, patterns, compact slots, work lists ----------------
#define MT 128
__global__ void meta_kernel(const int* __restrict__ node_ids,
                            const int* __restrict__ left,
                            const int* __restrict__ right,
                            const int* __restrict__ last,
                            int* __restrict__ counts,
                            int* __restrict__ rootSlot,
                            int4* __restrict__ lists) {
    __shared__ int  sHei[MT][17];
    __shared__ int  sRef[MT][17];
    __shared__ int4 ebuf[MT][7];
    __shared__ int  ebin[MT][7];
    __shared__ int  locCnt[19];
    __shared__ int  basePos[19];
    __shared__ int  scanBuf[MT];
    __shared__ int  blockBase;

    int tid = threadIdx.x;
    if (tid < 19) locCnt[tid] = 0;
    __syncthreads();

    int v = blockIdx.x * MT + tid;
    int nInt = 0;
    if (v < V) {
        int l15[LL], r15[LL], id15[LL];
#pragma unroll
        for (int j = 0; j < LL; ++j) {
            l15[j]  = left[v * LL + j];
            r15[j]  = right[v * LL + j];
            id15[j] = node_ids[v * LL + j];
        }
        int lastv = last[v];
#pragma unroll
        for (int j = 0; j < LL; ++j) {
            if (j <= lastv) {
                int l = l15[j];
                if (l < 0) {
                    sHei[tid][j] = 0;
                    sRef[tid][j] = LEAF_BIT | id15[j];
                } else {
                    int r = r15[j];
                    int hl = sHei[tid][l], hr = sHei[tid][r];
                    int hh = 1 + (hl > hr ? hl : hr);
                    sHei[tid][j] = hh;
                    int rl = sRef[tid][l], rr = sRef[tid][r];
                    int lLeaf = (rl >> 30) & 1, rLeaf = (rr >> 30) & 1;
                    int bin; int4 e;
                    e.x = nInt; e.y = id15[j];
                    if (hh == 1)              { bin = 0;                    e.z = rl; e.w = rr; }
                    else if (!lLeaf && rLeaf) { bin = 1 + (hh - 2) * 3;     e.z = rl; e.w = rr; }
                    else if (lLeaf && !rLeaf) { bin = 1 + (hh - 2) * 3 + 1; e.z = rr; e.w = rl; } // (intSlot, leafId)
                    else                      { bin = 1 + (hh - 2) * 3 + 2; e.z = rl; e.w = rr; }
                    int pos = atomicAdd(&locCnt[bin], 1);
                    ebuf[tid][nInt] = e;
                    ebin[tid][nInt] = (bin << 16) | pos;
                    sRef[tid][j] = nInt;    // local slot index
                    ++nInt;
                }
            }
        }
    }
    // block-level inclusive scan of nInt -> compact slot bases
    scanBuf[tid] = nInt;
    __syncthreads();
    for (int d = 1; d < MT; d <<= 1) {
        int val = (tid >= d) ? scanBuf[tid - d] : 0;
        __syncthreads();
        scanBuf[tid] += val;
        __syncthreads();
    }
    if (tid == 0) blockBase = atomicAdd(&counts[31], scanBuf[MT - 1]);
    if (tid < 19) {
        int c = locCnt[tid];
        basePos[tid] = c ? atomicAdd(&counts[tid], c) : 0;
    }
    __syncthreads();
    int treeBase = blockBase + scanBuf[tid] - nInt;
    if (v < V) rootSlot[v] = treeBase + nInt - 1;
    for (int e = 0; e < nInt; ++e) {
        int4 E  = ebuf[tid][e];
        int md  = ebin[tid][e];
        int bin = md >> 16, pos = md & 0xFFFF;
        E.x += treeBase;
        E.z = (E.z & LEAF_BIT) ? (E.z & REF_MASK) : (E.z + treeBase);
        E.w = (E.w & LEAF_BIT) ? (E.w & REF_MASK) : (E.w + treeBase);
        lists[d_binOff[bin] + basePos[bin] + pos] = E;
    }
}

// ---------------- h1: both children leaves -> pure table gather-add ----------------
// 32 threads per node, 4 dims each; wide loads, deep ILP; grid-stride.
__global__ void h1_kernel(const int4* __restrict__ list, const int* __restrict__ cntPtr,
                          const float* __restrict__ emb,
                          const __half* __restrict__ LT, const __half* __restrict__ RT,
                          const float* __restrict__ leafC,
                          float* __restrict__ hInt, float* __restrict__ cInt) {
    int cnt = *cntPtr;
    int j = threadIdx.x & 31;           // dim group: dims 4j..4j+3
    for (int n = blockIdx.x * 16 + (threadIdx.x >> 5); n < cnt; n += gridDim.x * 16) {
        int4 E = list[n];               // (dst, id, lid, rid)
        float4 ev[5]; uint2 lv[5], rv[5];
        const float* eb = emb + E.y * 640 + 4 * j;
        const uint2* lb = (const uint2*)(LT + E.z * 640) + j;   // 4 halves per uint2
        const uint2* rb = (const uint2*)(RT + E.w * 640) + j;
#pragma unroll
        for (int g = 0; g < 5; ++g) {
            ev[g] = *(const float4*)(eb + g * 128);
            lv[g] = lb[g * 32];
            rv[g] = rb[g * 32];
        }
        float4 cl4 = *(const float4*)(leafC + E.z * 128 + 4 * j);
        float4 cr4 = *(const float4*)(leafC + E.w * 128 + 4 * j);
        float4 co, ho;
#pragma unroll
        for (int u = 0; u < 4; ++u) {
            float s[5];
#pragma unroll
            for (int g = 0; g < 5; ++g) {
                __half2 lh = (u < 2) ? *(__half2*)&lv[g].x : *(__half2*)&lv[g].y;
                __half2 rh = (u < 2) ? *(__half2*)&rv[g].x : *(__half2*)&rv[g].y;
                float lf = (u & 1) ? __high2float(lh) : __low2float(lh);
                float rf = (u & 1) ? __high2float(rh) : __low2float(rh);
                s[g] = (&ev[g].x)[u] + lf + rf;
            }
            float cl = (&cl4.x)[u], cr = (&cr4.x)[u];
            float c = sigm(s[0]) * tanhf(s[4]) + sigm(s[1]) * cl + sigm(s[2]) * cr;
            float h = sigm(s[3]) * tanhf(c);
            (&co.x)[u] = c; (&ho.x)[u] = h;
        }
        *(float4*)(cInt + E.x * 128 + 4 * j) = co;
        *(float4*)(hInt + E.x * 128 + 4 * j) = ho;
    }
}

// ---------------- gathered GEMMs for height rounds (8-node chunks) ----------------
// one internal child: K=128, leaf side from fp16 table. entry = (dst, id, intSlot, leafId)
__device__ void gemm_one(const int4* __restrict__ list, int cnt, int blk,
                         const float* __restrict__ W, const float* __restrict__ Wb,
                         const __half* __restrict__ tab, bool intLeft,
                         const float* __restrict__ emb, const float* __restrict__ leafC,
                         float* __restrict__ hInt, float* __restrict__ cInt,
                         float* A, float* CH, int4* meta) {
    int base = blk * 8;
    int rows = cnt - base; if (rows > 8) rows = 8;
    int t = threadIdx.x;
    if (t < 8) meta[t] = list[base + (t < rows ? t : 0)];
    __syncthreads();
    for (int idx = t; idx < 8 * 128; idx += 320) {
        int m = idx >> 7, k = idx & 127;
        A[idx] = hInt[meta[m].z * 128 + k];
    }
    float b0 = Wb[2 * t], b1 = Wb[2 * t + 1];
    float acc0[8], acc1[8];
#pragma unroll
    for (int m = 0; m < 8; ++m) {
        const float* e = emb + meta[m].y * 640;
        float2 tf = __half22float2(((const __half2*)tab)[meta[m].w * 320 + t]);
        acc0[m] = e[2 * t]     + tf.x + b0;
        acc1[m] = e[2 * t + 1] + tf.y + b1;
    }
    __syncthreads();
    const float* Bp = W + 2 * t;
#pragma unroll 1
    for (int kb = 0; kb < 128; kb += 4) {
        float4 a[8];
#pragma unroll
        for (int m = 0; m < 8; ++m) a[m] = *(const float4*)(A + (m << 7) + kb);
        float2 bb[4];
#pragma unroll
        for (int u = 0; u < 4; ++u) bb[u] = *(const float2*)(Bp + (kb + u) * 640);
#pragma unroll
        for (int u = 0; u < 4; ++u)
#pragma unroll
            for (int m = 0; m < 8; ++m) {
                float av = (&a[m].x)[u];
                acc0[m] = fmaf(av, bb[u].x, acc0[m]);
                acc1[m] = fmaf(av, bb[u].y, acc1[m]);
            }
    }
#pragma unroll 1
    for (int c0 = 0; c0 < 8; c0 += 4) {
        __syncthreads();
#pragma unroll
        for (int m = 0; m < 4; ++m)
            *(float2*)(CH + m * 640 + 2 * t) = make_float2(acc0[c0 + m], acc1[c0 + m]);
        __syncthreads();
        for (int it = t; it < 4 * 128; it += 320) {
            int mm = it >> 7, m = c0 + mm;
            if (m < rows) {
                int i = it & 127;
                const float* Sm = CH + mm * 640;
                float cI = cInt[meta[m].z * 128 + i];
                float cL = leafC[meta[m].w * 128 + i];
                float cl = intLeft ? cI : cL;
                float cr = intLeft ? cL : cI;
                float c = sigm(Sm[i]) * tanhf(Sm[512 + i])
                        + sigm(Sm[128 + i]) * cl + sigm(Sm[256 + i]) * cr;
                float h = sigm(Sm[384 + i]) * tanhf(c);
                int dst = meta[m].x;
                cInt[dst * 128 + i] = c;
                hInt[dst * 128 + i] = h;
            }
        }
    }
}

// two internal children: K=256. entry = (dst, id, lslot, rslot)
__device__ void gemm_two(const int4* __restrict__ list, int cnt, int blk,
                         const float* __restrict__ Wl, const float* __restrict__ Wlb,
                         const float* __restrict__ Wr, const float* __restrict__ Wrb,
                         const float* __restrict__ emb,
                         float* __restrict__ hInt, float* __restrict__ cInt,
                         float* A, float* CH, int4* meta) {
    int base = blk * 8;
    int rows = cnt - base; if (rows > 8) rows = 8;
    int t = threadIdx.x;
    if (t < 8) meta[t] = list[base + (t < rows ? t : 0)];
    __syncthreads();
    for (int idx = t; idx < 8 * 256; idx += 320) {
        int m = idx >> 8, k = idx & 255;
        int ref = (k < 128) ? meta[m].z : meta[m].w;
        A[idx] = hInt[ref * 128 + (k & 127)];
    }
    float b0 = Wlb[2 * t] + Wrb[2 * t], b1 = Wlb[2 * t + 1] + Wrb[2 * t + 1];
    float acc0[8], acc1[8];
#pragma unroll
    for (int m = 0; m < 8; ++m) {
        const float* e = emb + meta[m].y * 640;
        acc0[m] = e[2 * t] + b0;
        acc1[m] = e[2 * t + 1] + b1;
    }
    __syncthreads();
#pragma unroll 1
    for (int half = 0; half < 2; ++half) {
        const float* Bp = (half ? Wr : Wl) + 2 * t;
        const float* Ab = A + half * 128;
#pragma unroll 1
        for (int kb = 0; kb < 128; kb += 4) {
            float4 a[8];
#pragma unroll
            for (int m = 0; m < 8; ++m) a[m] = *(const float4*)(Ab + (m << 8) + kb);
            float2 bb[4];
#pragma unroll
            for (int u = 0; u < 4; ++u) bb[u] = *(const float2*)(Bp + (kb + u) * 640);
#pragma unroll
            for (int u = 0; u < 4; ++u)
#pragma unroll
                for (int m = 0; m < 8; ++m) {
                    float av = (&a[m].x)[u];
                    acc0[m] = fmaf(av, bb[u].x, acc0[m]);
                    acc1[m] = fmaf(av, bb[u].y, acc1[m]);
                }
        }
    }
#pragma unroll 1
    for (int c0 = 0; c0 < 8; c0 += 4) {
        __syncthreads();
#pragma unroll
        for (int m = 0; m < 4; ++m)
            *(float2*)(CH + m * 640 + 2 * t) = make_float2(acc0[c0 + m], acc1[c0 + m]);
        __syncthreads();
        for (int it = t; it < 4 * 128; it += 320) {
            int mm = it >> 7, m = c0 + mm;
            if (m < rows) {
                int i = it & 127;
                const float* Sm = CH + mm * 640;
                float cl = cInt[meta[m].z * 128 + i];
                float cr = cInt[meta[m].w * 128 + i];
                float c = sigm(Sm[i]) * tanhf(Sm[512 + i])
                        + sigm(Sm[128 + i]) * cl + sigm(Sm[256 + i]) * cr;
                float h = sigm(Sm[384 + i]) * tanhf(c);
                int dst = meta[m].x;
                cInt[dst * 128 + i] = c;
                hInt[dst * 128 + i] = h;
            }
        }
    }
}

// One persistent grid per round; grid-strides over the unified chunk space of
// the round's three bins (8 nodes per chunk).
__launch_bounds__(320)
__global__ void round_kernel(const int4* __restrict__ l1,
                             const int4* __restrict__ l2,
                             const int4* __restrict__ l3,
                             const int* __restrict__ counts, int bi,
                             const float* __restrict__ emb,
                             const float* __restrict__ Wl, const float* __restrict__ Wlb,
                             const float* __restrict__ Wr, const float* __restrict__ Wrb,
                             const __half* __restrict__ LT, const __half* __restrict__ RT,
                             const float* __restrict__ leafC,
                             float* __restrict__ hInt, float* __restrict__ cInt) {
    __shared__ float A[8 * 256];
    __shared__ float CH[4 * 640];
    __shared__ int4  meta[8];
    int c1 = counts[bi], c2 = counts[bi + 1], c3 = counts[bi + 2];
    int nb1 = (c1 + 7) >> 3, nb2 = (c2 + 7) >> 3, nb3 = (c3 + 7) >> 3;
    int total = nb1 + nb2 + nb3;
    for (int chunk = blockIdx.x; chunk < total; chunk += gridDim.x) {
        if (chunk < nb1)
            gemm_one(l1, c1, chunk, Wl, Wlb, RT, true, emb, leafC, hInt, cInt, A, CH, meta);
        else if (chunk < nb1 + nb2)
            gemm_one(l2, c2, chunk - nb1, Wr, Wrb, LT, false, emb, leafC, hInt, cInt, A, CH, meta);
        else
            gemm_two(l3, c3, chunk - nb1 - nb2, Wl, Wlb, Wr, Wrb, emb, hInt, cInt, A, CH, meta);
        __syncthreads();   // protect meta/A/CH reuse across chunks
    }
}

// ---------------- final gather: out[b,s,:] = h_root[input[b,s]] ----------------
__global__ void gather_kernel(const int* __restrict__ input,
                              const int* __restrict__ rootSlot,
                              const float* __restrict__ hInt,
                              float4* __restrict__ out) {
    int idx = blockIdx.x * 256 + threadIdx.x;   // < OUTN/4
    int token = input[idx >> 5];
    int d = idx & 31;
    out[idx] = ((const float4*)hInt)[rootSlot[token] * 32 + d];
}

extern "C" void kernel_launch(void* const* d_in, const int* in_sizes, int n_in,
                              void* d_out, int out_size, void* d_ws, size_t ws_size,
                              hipStream_t stream) {
    const int*   input    = (const int*)d_in[0];
    const int*   node_ids = (const int*)d_in[1];
    const int*   left     = (const int*)d_in[2];
    const int*   right    = (const int*)d_in[3];
    const int*   last     = (const int*)d_in[4];
    const float* emb      = (const float*)d_in[5];
    const float* Wl       = (const float*)d_in[6];
    const float* Wlb      = (const float*)d_in[7];
    const float* Wr       = (const float*)d_in[8];
    const float* Wrb      = (const float*)d_in[9];
    float* out = (float*)d_out;

    char* ws = (char*)d_ws;
    int*    counts   = (int*)(ws + OFF_COUNTS);
    int*    rootSlot = (int*)(ws + OFF_ROOT);
    int4*   lists    = (int4*)(ws + OFF_LISTS);
    float*  leafH    = (float*)(ws + OFF_LEAFH);
    float*  leafC    = (float*)(ws + OFF_LEAFC);
    __half* LTp      = (__half*)(ws + OFF_LT);
    __half* RTp      = (__half*)(ws + OFF_RT);
    float*  hInt     = (float*)(ws + OFF_HINT);
    float*  cInt     = (float*)(ws + OFF_CINT);

    (void)hipMemsetAsync(counts, 0, 128, stream);

    leaf_kernel<<<SCV, 128, 0, stream>>>(emb, leafH, leafC);
    table_kernel<<<dim3(SCV / 16, 2), 320, 0, stream>>>(leafH, Wl, Wlb, Wr, Wrb, LTp, RTp);
    meta_kernel<<<(V + MT - 1) / MT, MT, 0, stream>>>(node_ids, left, right, last,
                                                      counts, rootSlot, lists);

    h1_kernel<<<H1_BLOCKS, 512, 0, stream>>>(lists, counts, emb, LTp, RTp, leafC, hInt, cInt);

    static const int binOffH[19] = {
        0,
        80000, 120000, 160000,
        200000, 240000, 280000,
        320000, 340000, 360000,
        380000, 400000, 420000,
        440000, 460000, 480000,
        500000, 520000, 540000
    };
    for (int h = 2; h <= 7; ++h) {
        int bi = 1 + (h - 2) * 3;
        round_kernel<<<ROUND_BLOCKS, 320, 0, stream>>>(
            lists + binOffH[bi], lists + binOffH[bi + 1], lists + binOffH[bi + 2],
            counts, bi,
            emb, Wl, Wlb, Wr, Wrb, LTp, RTp, leafC, hInt, cInt);
    }

    gather_kernel<<<OUTN / 4 / 256, 256, 0, stream>>>(input, rootSlot, hInt, (float4*)out);
}

// Round 7
// 370.815 us; speedup vs baseline: 4.4307x; 1.2907x over previous
//
#include <hip/hip_runtime.h>
#include <hip/hip_fp16.h>
#include <math.h>

// Problem constants
#define V    20000
#define SCV  4000
#define LL   15
#define OUTN (16384 * 128)   // B*S*D

#define LEAF_BIT 0x40000000
#define REF_MASK 0x3FFFFFFF
#define DUMMY_SLOT 89999     // total internal nodes ~80k < 89999

// ---- workspace layout (bytes) ----
// counts int[32] @0 ; rootSlot int[V] @128 ; lists int4[240000] @80384
// leafH f32[4000*128] @3920384 ; leafC f32 @5968384 ; leafHh fp16 @8016384
// LT fp16[4000*640] @9040384 ; RT @14160384 ; WT fp16[640*256] @19280384
// biasSum f32[640] @19608064 ; hInt f32[90000*128] @19610624
// cInt f32 @65690624 ; hHalf fp16 @111770624  (ends ~134.8 MB)
#define OFF_COUNTS 0
#define OFF_ROOT   128
#define OFF_LISTS  80384
#define OFF_LEAFH  3920384
#define OFF_LEAFC  5968384
#define OFF_LEAFHH 8016384
#define OFF_LT     9040384
#define OFF_RT     14160384
#define OFF_WT     19280384
#define OFF_BIAS   19608064
#define OFF_HINT   19610624
#define OFF_CINT   65690624
#define OFF_HH     111770624

// per-height lists: h1@0 (cap 80000), h2@80000 (40000), h3@120000 (40000),
// h4@160000, h5@180000, h6@200000, h7@220000 (20000 each)
__device__ __constant__ int d_listOff[8] = {0, 0, 80000, 120000, 160000, 180000, 200000, 220000};

#define ROUND_BLOCKS 1280
#define H1_BLOCKS    1920

typedef _Float16 f16x8 __attribute__((ext_vector_type(8)));
typedef float    f32x4 __attribute__((ext_vector_type(4)));

__device__ __forceinline__ float sigm(float x) { return 1.0f / (1.0f + expf(-x)); }

// ---------------- leaf kernel: per sub-char-id leaf (h,c) + fp16 h ----------------
__global__ void leaf_kernel(const float* __restrict__ emb,
                            float* __restrict__ leafH, float* __restrict__ leafC,
                            __half* __restrict__ leafHh) {
    int row = blockIdx.x;       // 0..SCV-1
    int i   = threadIdx.x;      // 0..127
    const float* e = emb + row * 640;
    float ig = e[i];
    float og = e[384 + i];
    float ug = e[512 + i];
    float c = sigm(ig) * tanhf(ug);
    float h = sigm(og) * tanhf(c);
    leafH[row * 128 + i] = h;
    leafC[row * 128 + i] = c;
    leafHh[row * 128 + i] = __float2half(h);
}

// ---------------- table kernel: LT/RT fp16 tables (for h1 only) ----------------
__launch_bounds__(320)
__global__ void table_kernel(const float* __restrict__ leafH,
                             const float* __restrict__ Wl, const float* __restrict__ Wlb,
                             const float* __restrict__ Wr, const float* __restrict__ Wrb,
                             __half* __restrict__ LT, __half* __restrict__ RT) {
    __shared__ float A[16 * 128];
    int which = blockIdx.y;
    const float* W  = which ? Wr : Wl;
    const float* Wb = which ? Wrb : Wlb;
    __half* OUT     = which ? RT : LT;
    int r0 = blockIdx.x * 16;
    int t = threadIdx.x;
    for (int idx = t; idx < 16 * 128; idx += 320) A[idx] = leafH[r0 * 128 + idx];
    float acc0[16], acc1[16];
    float b0 = Wb[2 * t], b1 = Wb[2 * t + 1];
#pragma unroll
    for (int m = 0; m < 16; ++m) { acc0[m] = b0; acc1[m] = b1; }
    __syncthreads();
    const float* Bp = W + 2 * t;
#pragma unroll 1
    for (int kb = 0; kb < 128; kb += 4) {
        float4 a[16];
#pragma unroll
        for (int m = 0; m < 16; ++m) a[m] = *(const float4*)(A + (m << 7) + kb);
        float2 bb[4];
#pragma unroll
        for (int u = 0; u < 4; ++u) bb[u] = *(const float2*)(Bp + (kb + u) * 640);
#pragma unroll
        for (int u = 0; u < 4; ++u)
#pragma unroll
            for (int m = 0; m < 16; ++m) {
                float av = (&a[m].x)[u];
                acc0[m] = fmaf(av, bb[u].x, acc0[m]);
                acc1[m] = fmaf(av, bb[u].y, acc1[m]);
            }
    }
#pragma unroll
    for (int m = 0; m < 16; ++m)
        ((__half2*)OUT)[(r0 + m) * 320 + t] = __float22half2_rn(make_float2(acc0[m], acc1[m]));
}

// ---------------- WT kernel: WT[n][k] = fp16([Wl;Wr][k][n]), LDS transpose ----------------
__global__ void wt_kernel(const float* __restrict__ Wl, const float* __restrict__ Wr,
                          __half* __restrict__ WT) {
    __shared__ float T[64][65];
    int kb = blockIdx.x * 64, nb = blockIdx.y * 64;
    int tx = threadIdx.x & 63, ty = threadIdx.x >> 6;   // 256 threads
    for (int kk = ty; kk < 64; kk += 4) {
        int k = kb + kk;
        const float* Wsrc = (k < 128) ? (Wl + k * 640) : (Wr + (k - 128) * 640);
        T[kk][tx] = Wsrc[nb + tx];
    }
    __syncthreads();
    for (int nn = ty; nn < 64; nn += 4)
        WT[(nb + nn) * 256 + kb + tx] = __float2half(T[tx][nn]);
}

__global__ void bias_kernel(const float* __restrict__ Wlb, const float* __restrict__ Wrb,
                            float* __restrict__ biasSum) {
    int i = threadIdx.x;   // 640
    biasSum[i] = Wlb[i] + Wrb[i];
}

// ---------------- metadata: heights, compact slots, per-height lists ----------------
#define MT 128
__global__ void meta_kernel(const int* __restrict__ node_ids,
                            const int* __restrict__ left,
                            const int* __restrict__ right,
                            const int* __restrict__ last,
                            int* __restrict__ counts,
                            int* __restrict__ rootSlot,
                            int4* __restrict__ lists) {
    __shared__ int  sHei[MT][17];
    __shared__ int  sRef[MT][17];
    __shared__ int4 ebuf[MT][7];
    __shared__ int  ebin[MT][7];
    __shared__ int  locCnt[8];
    __shared__ int  basePos[8];
    __shared__ int  scanBuf[MT];
    __shared__ int  blockBase;

    int tid = threadIdx.x;
    if (tid < 8) locCnt[tid] = 0;
    __syncthreads();

    int v = blockIdx.x * MT + tid;
    int nInt = 0;
    if (v < V) {
        int l15[LL], r15[LL], id15[LL];
#pragma unroll
        for (int j = 0; j < LL; ++j) {
            l15[j]  = left[v * LL + j];
            r15[j]  = right[v * LL + j];
            id15[j] = node_ids[v * LL + j];
        }
        int lastv = last[v];
#pragma unroll
        for (int j = 0; j < LL; ++j) {
            if (j <= lastv) {
                int l = l15[j];
                if (l < 0) {
                    sHei[tid][j] = 0;
                    sRef[tid][j] = LEAF_BIT | id15[j];
                } else {
                    int r = r15[j];
                    int hl = sHei[tid][l], hr = sHei[tid][r];
                    int hh = 1 + (hl > hr ? hl : hr);
                    sHei[tid][j] = hh;
                    int pos = atomicAdd(&locCnt[hh], 1);
                    ebuf[tid][nInt] = make_int4(nInt, id15[j], sRef[tid][l], sRef[tid][r]);
                    ebin[tid][nInt] = (hh << 16) | pos;
                    sRef[tid][j] = nInt;    // local slot index (no LEAF_BIT)
                    ++nInt;
                }
            }
        }
    }
    // block-level inclusive scan of nInt -> compact slot bases
    scanBuf[tid] = nInt;
    __syncthreads();
    for (int d = 1; d < MT; d <<= 1) {
        int val = (tid >= d) ? scanBuf[tid - d] : 0;
        __syncthreads();
        scanBuf[tid] += val;
        __syncthreads();
    }
    if (tid == 0) blockBase = atomicAdd(&counts[31], scanBuf[MT - 1]);
    if (tid < 8) {
        int c = locCnt[tid];
        basePos[tid] = c ? atomicAdd(&counts[tid], c) : 0;
    }
    __syncthreads();
    int treeBase = blockBase + scanBuf[tid] - nInt;
    if (v < V) rootSlot[v] = treeBase + nInt - 1;
    for (int e = 0; e < nInt; ++e) {
        int4 E  = ebuf[tid][e];
        int md  = ebin[tid][e];
        int hh  = md >> 16, pos = md & 0xFFFF;
        E.x += treeBase;
        E.z = (E.z & LEAF_BIT) ? E.z : (E.z + treeBase);   // keep leaf tag
        E.w = (E.w & LEAF_BIT) ? E.w : (E.w + treeBase);
        lists[d_listOff[hh] + basePos[hh] + pos] = E;
    }
}

// ---------------- h1: both children leaves -> pure table gather-add ----------------
__global__ void h1_kernel(const int4* __restrict__ list, const int* __restrict__ cntPtr,
                          const float* __restrict__ emb,
                          const __half* __restrict__ LT, const __half* __restrict__ RT,
                          const float* __restrict__ leafC,
                          float* __restrict__ hInt, float* __restrict__ cInt,
                          __half* __restrict__ hH) {
    int cnt = *cntPtr;
    int j = threadIdx.x & 31;           // dim group: dims 4j..4j+3
    for (int n = blockIdx.x * 16 + (threadIdx.x >> 5); n < cnt; n += gridDim.x * 16) {
        int4 E = list[n];               // (dst, id, LEAF|lid, LEAF|rid)
        int li = E.z & REF_MASK, ri = E.w & REF_MASK;
        float4 ev[5]; uint2 lv[5], rv[5];
        const float* eb = emb + E.y * 640 + 4 * j;
        const uint2* lb = (const uint2*)(LT + li * 640) + j;
        const uint2* rb = (const uint2*)(RT + ri * 640) + j;
#pragma unroll
        for (int g = 0; g < 5; ++g) {
            ev[g] = *(const float4*)(eb + g * 128);
            lv[g] = lb[g * 32];
            rv[g] = rb[g * 32];
        }
        float4 cl4 = *(const float4*)(leafC + li * 128 + 4 * j);
        float4 cr4 = *(const float4*)(leafC + ri * 128 + 4 * j);
        float4 co, ho;
#pragma unroll
        for (int u = 0; u < 4; ++u) {
            float s[5];
#pragma unroll
            for (int g = 0; g < 5; ++g) {
                __half2 lh = (u < 2) ? *(__half2*)&lv[g].x : *(__half2*)&lv[g].y;
                __half2 rh = (u < 2) ? *(__half2*)&rv[g].x : *(__half2*)&rv[g].y;
                float lf = (u & 1) ? __high2float(lh) : __low2float(lh);
                float rf = (u & 1) ? __high2float(rh) : __low2float(rh);
                s[g] = (&ev[g].x)[u] + lf + rf;
            }
            float cl = (&cl4.x)[u], cr = (&cr4.x)[u];
            float c = sigm(s[0]) * tanhf(s[4]) + sigm(s[1]) * cl + sigm(s[2]) * cr;
            float h = sigm(s[3]) * tanhf(c);
            (&co.x)[u] = c; (&ho.x)[u] = h;
        }
        *(float4*)(cInt + E.x * 128 + 4 * j) = co;
        *(float4*)(hInt + E.x * 128 + 4 * j) = ho;
        __half2 h0 = __float22half2_rn(make_float2(ho.x, ho.y));
        __half2 h1v = __float22half2_rn(make_float2(ho.z, ho.w));
        uint2 hp; hp.x = *(unsigned int*)&h0; hp.y = *(unsigned int*)&h1v;
        *(uint2*)(hH + E.x * 128 + 4 * j) = hp;
    }
}

// ---------------- MFMA round: all h>=2 nodes, unified K=256 ----------------
// chunk = 16 nodes. A = [h_l | h_r] fp16 in LDS; B = WT[640][256] fp16 from L2.
// wave w owns col-tiles {w+4p}; gates of a dim are 8 tiles apart (mult of 4)
// -> full LSTM epilogue in registers.
__launch_bounds__(256)
__global__ void round_mfma(const int4* __restrict__ list, const int* __restrict__ cntPtr,
                           const float* __restrict__ emb, const __half* __restrict__ WT,
                           const float* __restrict__ biasSum,
                           const __half* __restrict__ leafHh, const float* __restrict__ leafC,
                           float* __restrict__ hInt, float* __restrict__ cInt,
                           __half* __restrict__ hH) {
    __shared__ __half Ah[16][264];   // +8 fp16 pad: 2-way-only bank aliasing on b128
    __shared__ int4 meta[16];
    int cnt = *cntPtr;
    int nChunks = (cnt + 15) >> 4;
    int t = threadIdx.x;
    int lane = t & 63, wave = t >> 6;        // 4 waves
    int ln15 = lane & 15, quad = lane >> 4;
    for (int chunk = blockIdx.x; chunk < nChunks; chunk += gridDim.x) {
        int base = chunk * 16;
        int rows = cnt - base; if (rows > 16) rows = 16;
        if (t < 16) {
            int4 E;
            if (t < rows) E = list[base + t];
            else { E.x = DUMMY_SLOT; E.y = 0; E.z = LEAF_BIT; E.w = LEAF_BIT; }
            meta[t] = E;
        }
        __syncthreads();
        // stage A rows: [hl fp16 (k 0..127) | hr fp16 (k 128..255)]
        for (int idx = t; idx < 512; idx += 256) {
            int m = idx >> 5, q = idx & 31;
            int ref = (q < 16) ? meta[m].z : meta[m].w;
            const __half* hs = (ref & LEAF_BIT) ? leafHh : hH;
            uint4 v = *(const uint4*)(hs + (ref & REF_MASK) * 128 + (q & 15) * 8);
            *(uint4*)(&Ah[m][q * 8]) = v;
        }
        // C init: emb + (Wlb+Wrb)
        f32x4 acc[10];
#pragma unroll
        for (int p = 0; p < 10; ++p) {
            int col = (wave + 4 * p) * 16 + ln15;
            float bs = biasSum[col];
#pragma unroll
            for (int r = 0; r < 4; ++r)
                acc[p][r] = emb[meta[quad * 4 + r].y * 640 + col] + bs;
        }
        __syncthreads();
        // K loop: 8 steps of 32, A frag shared across the wave's 10 col-tiles
#pragma unroll 1
        for (int kb = 0; kb < 8; ++kb) {
            f16x8 af = *(const f16x8*)((const void*)&Ah[ln15][kb * 32 + quad * 8]);
#pragma unroll
            for (int p = 0; p < 10; ++p) {
                const __half* bp = WT + ((wave + 4 * p) * 16 + ln15) * 256 + kb * 32 + quad * 8;
                f16x8 bf = *(const f16x8*)((const void*)bp);
                acc[p] = __builtin_amdgcn_mfma_f32_16x16x32_f16(af, bf, acc[p], 0, 0, 0);
            }
        }
        // in-register LSTM epilogue: gates ig,lfg,rfg,og,ug at p = g, g+2, g+4, g+6, g+8
#pragma unroll
        for (int g = 0; g < 2; ++g) {
            int d = (wave + 4 * g) * 16 + ln15;   // dim in [0,128)
#pragma unroll
            for (int r = 0; r < 4; ++r) {
                int4 E = meta[quad * 4 + r];
                float ig = acc[g][r],     lfg = acc[g + 2][r], rfg = acc[g + 4][r];
                float og = acc[g + 6][r], ug  = acc[g + 8][r];
                float cl = ((E.z & LEAF_BIT) ? leafC : cInt)[(E.z & REF_MASK) * 128 + d];
                float cr = ((E.w & LEAF_BIT) ? leafC : cInt)[(E.w & REF_MASK) * 128 + d];
                float c = sigm(ig) * tanhf(ug) + sigm(lfg) * cl + sigm(rfg) * cr;
                float h = sigm(og) * tanhf(c);
                cInt[E.x * 128 + d] = c;
                hInt[E.x * 128 + d] = h;
                hH[E.x * 128 + d] = __float2half(h);
            }
        }
        __syncthreads();   // protect meta/Ah before next chunk
    }
}

// ---------------- final gather: out[b,s,:] = h_root[input[b,s]] ----------------
__global__ void gather_kernel(const int* __restrict__ input,
                              const int* __restrict__ rootSlot,
                              const float* __restrict__ hInt,
                              float4* __restrict__ out) {
    int idx = blockIdx.x * 256 + threadIdx.x;   // < OUTN/4
    int token = input[idx >> 5];
    int d = idx & 31;
    out[idx] = ((const float4*)hInt)[rootSlot[token] * 32 + d];
}

extern "C" void kernel_launch(void* const* d_in, const int* in_sizes, int n_in,
                              void* d_out, int out_size, void* d_ws, size_t ws_size,
                              hipStream_t stream) {
    const int*   input    = (const int*)d_in[0];
    const int*   node_ids = (const int*)d_in[1];
    const int*   left     = (const int*)d_in[2];
    const int*   right    = (const int*)d_in[3];
    const int*   last     = (const int*)d_in[4];
    const float* emb      = (const float*)d_in[5];
    const float* Wl       = (const float*)d_in[6];
    const float* Wlb      = (const float*)d_in[7];
    const float* Wr       = (const float*)d_in[8];
    const float* Wrb      = (const float*)d_in[9];
    float* out = (float*)d_out;

    char* ws = (char*)d_ws;
    int*    counts   = (int*)(ws + OFF_COUNTS);
    int*    rootSlot = (int*)(ws + OFF_ROOT);
    int4*   lists    = (int4*)(ws + OFF_LISTS);
    float*  leafH    = (float*)(ws + OFF_LEAFH);
    float*  leafC    = (float*)(ws + OFF_LEAFC);
    __half* leafHh   = (__half*)(ws + OFF_LEAFHH);
    __half* LTp      = (__half*)(ws + OFF_LT);
    __half* RTp      = (__half*)(ws + OFF_RT);
    __half* WT       = (__half*)(ws + OFF_WT);
    float*  biasSum  = (float*)(ws + OFF_BIAS);
    float*  hInt     = (float*)(ws + OFF_HINT);
    float*  cInt     = (float*)(ws + OFF_CINT);
    __half* hH       = (__half*)(ws + OFF_HH);

    (void)hipMemsetAsync(counts, 0, 128, stream);

    leaf_kernel<<<SCV, 128, 0, stream>>>(emb, leafH, leafC, leafHh);
    table_kernel<<<dim3(SCV / 16, 2), 320, 0, stream>>>(leafH, Wl, Wlb, Wr, Wrb, LTp, RTp);
    wt_kernel<<<dim3(4, 10), 256, 0, stream>>>(Wl, Wr, WT);
    bias_kernel<<<1, 640, 0, stream>>>(Wlb, Wrb, biasSum);
    meta_kernel<<<(V + MT - 1) / MT, MT, 0, stream>>>(node_ids, left, right, last,
                                                      counts, rootSlot, lists);

    h1_kernel<<<H1_BLOCKS, 512, 0, stream>>>(lists, counts + 1, emb, LTp, RTp, leafC,
                                             hInt, cInt, hH);

    static const int h_listOff[8] = {0, 0, 80000, 120000, 160000, 180000, 200000, 220000};
    for (int h = 2; h <= 7; ++h) {
        round_mfma<<<ROUND_BLOCKS, 256, 0, stream>>>(
            lists + h_listOff[h], counts + h,
            emb, WT, biasSum, leafHh, leafC, hInt, cInt, hH);
    }

    gather_kernel<<<OUTN / 4 / 256, 256, 0, stream>>>(input, rootSlot, hInt, (float4*)out);
}